// Round 4
// baseline (405.690 us; speedup 1.0000x reference)
//
#include <hip/hip_runtime.h>

// ---------- types ----------
typedef __attribute__((ext_vector_type(8))) __bf16 bf16x8;   // MFMA A/B frag (4 VGPR)
typedef __attribute__((ext_vector_type(4))) float f32x4;     // MFMA C/D frag
typedef __attribute__((ext_vector_type(8))) unsigned short u16x8;

// fp32 -> bf16 (RNE, no NaN inputs expected)
__device__ __forceinline__ ushort f2bf(float x) {
    unsigned u = __builtin_bit_cast(unsigned, x);
    unsigned r = u + 0x7fffu + ((u >> 16) & 1u);
    return (ushort)(r >> 16);
}
__device__ __forceinline__ float bf2f(ushort u) {
    unsigned v = ((unsigned)u) << 16;
    return __builtin_bit_cast(float, v);
}

// packed f32x2 -> bf16x2 (T12)
__device__ __forceinline__ unsigned cvtpk(float lo, float hi) {
    unsigned r;
    asm("v_cvt_pk_bf16_f32 %0, %1, %2" : "=v"(r) : "v"(lo), "v"(hi));
    return r;
}

// async global->LDS, 16B per lane. LDS dest = wave-uniform base + lane*16.
__device__ __forceinline__ void gload16(const void* g, void* l) {
    __builtin_amdgcn_global_load_lds(
        (const __attribute__((address_space(1))) void*)g,
        (__attribute__((address_space(3))) void*)l,
        16, 0, 0);
}

#define MFMA16(a, b, cIn) __builtin_amdgcn_mfma_f32_16x16x32_bf16((a), (b), (cIn), 0, 0, 0)

// ---------- conversion kernels (fused launches) ----------
__global__ __launch_bounds__(256) void cvt_kv(const float* __restrict__ a, ushort* __restrict__ ab,
                                              const float* __restrict__ bsrc, ushort* __restrict__ bb,
                                              int n4) {
    const int stride = gridDim.x * 256;
    for (int i = blockIdx.x * 256 + threadIdx.x; i < n4; i += stride) {
        float4 v = ((const float4*)a)[i];
        ushort4 o; o.x = f2bf(v.x); o.y = f2bf(v.y); o.z = f2bf(v.z); o.w = f2bf(v.w);
        ((ushort4*)ab)[i] = o;
    }
    for (int i = blockIdx.x * 256 + threadIdx.x; i < n4; i += stride) {
        float4 v = ((const float4*)bsrc)[i];
        ushort4 o; o.x = f2bf(v.x); o.y = f2bf(v.y); o.z = f2bf(v.z); o.w = f2bf(v.w);
        ((ushort4*)bb)[i] = o;
    }
}

__global__ __launch_bounds__(256) void cvt_weights(
    const float* __restrict__ s0, ushort* __restrict__ d0, int n0,
    const float* __restrict__ s1, ushort* __restrict__ d1, int n1,
    const float* __restrict__ s2, ushort* __restrict__ d2, int n2,
    const float* __restrict__ s3, ushort* __restrict__ d3, int n3,
    const float* __restrict__ s4, ushort* __restrict__ d4, int n4c) {
    const int stride = gridDim.x * 256;
    const int t0 = blockIdx.x * 256 + threadIdx.x;
#define CVT_SEG(S, D, N)                                                  \
    for (int i = t0; i < (N); i += stride) {                              \
        float4 v = ((const float4*)(S))[i];                               \
        ushort4 o; o.x = f2bf(v.x); o.y = f2bf(v.y);                      \
        o.z = f2bf(v.z); o.w = f2bf(v.w);                                 \
        ((ushort4*)(D))[i] = o;                                           \
    }
    CVT_SEG(s0, d0, n0) CVT_SEG(s1, d1, n1) CVT_SEG(s2, d2, n2)
    CVT_SEG(s3, d3, n3) CVT_SEG(s4, d4, n4c)
#undef CVT_SEG
}

// query (4096x1024 f32) -> cat buffer cols 0..1023 (row stride 2048, bf16)
__global__ __launch_bounds__(256) void cvt_query_cat(const float* __restrict__ in,
                                                     ushort* __restrict__ cat) {
    const int r = blockIdx.x, t = threadIdx.x;
    float4 v = ((const float4*)(in + (size_t)r * 1024))[t];
    ushort4 o;
    o.x = f2bf(v.x); o.y = f2bf(v.y); o.z = f2bf(v.z); o.w = f2bf(v.w);
    ((ushort4*)(cat + (size_t)r * 2048))[t] = o;
}

// ---------- GEMM: C = A(MxK,bf16) @ W(NxK,bf16)^T + bias ----------
// 128M x 64N x 64K tiles, 4 waves (2x2), wave tile 64x32, acc 4x2.
// Unroll-by-2 K loop: compile-time buffer selector -> all LDS ops use
// base-reg + imm offset; global stage pointers advance by +128 B/step.
template<int EPI>
__global__ __launch_bounds__(256) void gemm_bt(
    const ushort* __restrict__ A, int lda,
    const ushort* __restrict__ Bw, int ldb,
    const float* __restrict__ bias,
    ushort* __restrict__ o_bf, int ld0,
    float* __restrict__ o_f32,
    int K, float scale)
{
    __shared__ __align__(1024) char smem[49152];  // A: 2x16K @0; B: 2x8K @32768
    const int t = threadIdx.x, w = t >> 6, l = t & 63, g = l >> 4, c = l & 15;
    const int wr = w >> 1, wc = w & 1;
    const long m0 = (long)blockIdx.y * 128, n0 = (long)blockIdx.x * 64;
    const size_t ldaB = (size_t)lda * 2, ldbB = (size_t)ldb * 2;
    const int swz = (c & 7) << 4;
    const int o0 = w * 1024 + l * 16;

    auto gsrc = [&](const char* base, size_t ldB, long r0, int o) {
        const int row = o >> 7, cb = o & 127;
        return base + (size_t)(r0 + row) * ldB + (cb ^ ((row & 7) << 4));
    };
    const char* aP0 = gsrc((const char*)A, ldaB, m0, o0);
    const char* aP1 = gsrc((const char*)A, ldaB, m0, o0 + 4096);
    const char* aP2 = gsrc((const char*)A, ldaB, m0, o0 + 8192);
    const char* aP3 = gsrc((const char*)A, ldaB, m0, o0 + 12288);
    const char* bP0 = gsrc((const char*)Bw, ldbB, n0, o0);
    const char* bP1 = gsrc((const char*)Bw, ldbB, n0, o0 + 4096);

    // LDS read bases (XOR identity: kf flips bit 6 cleanly)
    const int aRd0 = (wr * 64 + c) * 128 + ((g * 16) ^ swz);
    const int aRd1 = aRd0 ^ 64;
    const int bRd0 = 32768 + (wc * 32 + c) * 128 + ((g * 16) ^ swz);
    const int bRd1 = bRd0 ^ 64;

    f32x4 acc[4][2];
#pragma unroll
    for (int i = 0; i < 4; ++i)
#pragma unroll
        for (int j = 0; j < 2; ++j) acc[i][j] = (f32x4)0.0f;

    // prologue: stage tile 0 -> buf 0
    gload16(aP0, smem + w * 1024);
    gload16(aP1, smem + 4096 + w * 1024);
    gload16(aP2, smem + 8192 + w * 1024);
    gload16(aP3, smem + 12288 + w * 1024);
    gload16(bP0, smem + 32768 + w * 1024);
    gload16(bP1, smem + 32768 + 4096 + w * 1024);
    aP0 += 128; aP1 += 128; aP2 += 128; aP3 += 128; bP0 += 128; bP1 += 128;
    __syncthreads();

#define GSTEP(CUR, PF)                                                          \
    {                                                                           \
        if (PF) {                                                               \
            gload16(aP0, smem + ((CUR) ^ 1) * 16384 + w * 1024);                \
            gload16(aP1, smem + ((CUR) ^ 1) * 16384 + 4096 + w * 1024);         \
            gload16(aP2, smem + ((CUR) ^ 1) * 16384 + 8192 + w * 1024);         \
            gload16(aP3, smem + ((CUR) ^ 1) * 16384 + 12288 + w * 1024);        \
            gload16(bP0, smem + 32768 + ((CUR) ^ 1) * 8192 + w * 1024);         \
            gload16(bP1, smem + 32768 + ((CUR) ^ 1) * 8192 + 4096 + w * 1024);  \
            aP0 += 128; aP1 += 128; aP2 += 128; aP3 += 128;                     \
            bP0 += 128; bP1 += 128;                                             \
        }                                                                       \
        _Pragma("unroll")                                                       \
        for (int kf = 0; kf < 2; ++kf) {                                        \
            const int ar = kf ? aRd1 : aRd0, br = kf ? bRd1 : bRd0;             \
            bf16x8 af0 = *(const bf16x8*)(smem + (CUR) * 16384 + 0 + ar);       \
            bf16x8 af1 = *(const bf16x8*)(smem + (CUR) * 16384 + 2048 + ar);    \
            bf16x8 af2 = *(const bf16x8*)(smem + (CUR) * 16384 + 4096 + ar);    \
            bf16x8 af3 = *(const bf16x8*)(smem + (CUR) * 16384 + 6144 + ar);    \
            bf16x8 bf0 = *(const bf16x8*)(smem + (CUR) * 8192 + 0 + br);        \
            bf16x8 bf1 = *(const bf16x8*)(smem + (CUR) * 8192 + 2048 + br);     \
            acc[0][0] = MFMA16(af0, bf0, acc[0][0]);                            \
            acc[0][1] = MFMA16(af0, bf1, acc[0][1]);                            \
            acc[1][0] = MFMA16(af1, bf0, acc[1][0]);                            \
            acc[1][1] = MFMA16(af1, bf1, acc[1][1]);                            \
            acc[2][0] = MFMA16(af2, bf0, acc[2][0]);                            \
            acc[2][1] = MFMA16(af2, bf1, acc[2][1]);                            \
            acc[3][0] = MFMA16(af3, bf0, acc[3][0]);                            \
            acc[3][1] = MFMA16(af3, bf1, acc[3][1]);                            \
        }                                                                       \
        __syncthreads();                                                        \
    }

    const int nkt = K >> 6;   // always even here (12/16/32)
    for (int kt = 0; kt < nkt; kt += 2) {
        GSTEP(0, kt + 1 < nkt)
        GSTEP(1, kt + 2 < nkt)
    }
#undef GSTEP

    // epilogue: C/D layout col = l&15, row = (l>>4)*4 + jj  [verified m89/m91]
#pragma unroll
    for (int i = 0; i < 4; ++i)
#pragma unroll
        for (int j = 0; j < 2; ++j) {
            const long col = n0 + wc * 32 + j * 16 + c;
            const float bs = bias[col];
            const long rowb = m0 + wr * 64 + i * 16 + g * 4;
            if (EPI == 1) {
                ushort4 o;
                o.x = f2bf(acc[i][j][0] + bs);
                o.y = f2bf(acc[i][j][1] + bs);
                o.z = f2bf(acc[i][j][2] + bs);
                o.w = f2bf(acc[i][j][3] + bs);
                *(ushort4*)(o_bf + col * (long)ld0 + rowb) = o;
            } else {
#pragma unroll
                for (int jj = 0; jj < 4; ++jj) {
                    const long row = rowb + jj;
                    const float v = acc[i][j][jj] + bs;
                    if (EPI == 0) {
                        o_bf[row * (long)ld0 + col] = f2bf(v * scale);
                    } else if (EPI == 2) {
                        o_f32[row * (long)ld0 + col] = v;
                        o_bf[row * 2048 + col] = f2bf(v);
                    } else { // EPI == 3 : silu
                        const float sv = v / (1.0f + __expf(-v));
                        o_bf[row * (long)ld0 + col] = f2bf(sv);
                    }
                }
            }
        }
}

// ---------- flash attention (swapped-QK^T, unrolled dbuf, base-reg addressing) ----------
// grid (S/64, H, B), 256 threads = 4 waves; wave owns 16 q-rows; KVBLK=64.
// qp PRE-SCALED by Dh^-0.5*log2(e); vT: 1024x(B*M) bf16 (transposed V).
// Lane (c,g) owns P[q=s0+c][k=mf*16+g*4+j]; denominator via ones-MFMA.
__global__ __launch_bounds__(256, 4) void attn_fwd(
    const ushort* __restrict__ qp, const ushort* __restrict__ kp,
    const ushort* __restrict__ vT, ushort* __restrict__ out)
{
    __shared__ __align__(1024) char smem[40960];
    // K: 2x8K @0; V: 2x8K @16384; P: 4 x 2K @32768
    const int t = threadIdx.x, w = t >> 6, l = t & 63, g = l >> 4, c = l & 15;
    const int b = blockIdx.z, h = blockIdx.y;
    const int s0 = blockIdx.x * 64 + w * 16;
    const int swz = (c & 7) << 4;

    const size_t qbase = ((size_t)b * 2048 + s0 + c) * 1024 + h * 64 + g * 8;
    const bf16x8 qf0 = *(const bf16x8*)(qp + qbase);
    const bf16x8 qf1 = *(const bf16x8*)(qp + qbase + 32);

    const u16x8 ones_u = (u16x8)(ushort)0x3F80;           // bf16 1.0 x8
    const bf16x8 ones = __builtin_bit_cast(bf16x8, ones_u);

    f32x4 oacc[4];
    f32x4 lacc = (f32x4)0.0f;
#pragma unroll
    for (int d = 0; d < 4; ++d) oacc[d] = (f32x4)0.0f;
    float mrow = -1e30f;

    // LDS base regs (XOR identities: kf/km flip bit 6; mf flips bits 5-6)
    const int kb0 = c * 128 + ((g * 16) ^ swz);
    const int kb1 = kb0 ^ 64;
    const int pw0 = 32768 + w * 2048 + c * 128 + ((g * 8) ^ swz);
    const int pwm1 = pw0 ^ 32, pwm2 = pw0 ^ 64, pwm3 = pw0 ^ 96;
    const int pr0 = 32768 + w * 2048 + kb0;
    const int pr1 = pr0 ^ 64;

    // global stage pointers (advance: K +131072 B, V +128 B per tile)
    const char* kpB = (const char*)kp + (size_t)b * 4096 * 2048 + h * 128;
    const char* vTB = (const char*)vT + (size_t)h * 64 * 16384 + (size_t)b * 4096 * 2;
    const int o0 = w * 1024 + l * 16;
    auto mksrc = [&](const char* base, size_t ldB, int o) {
        const int row = o >> 7, cb = o & 127;
        return base + (size_t)row * ldB + (cb ^ ((row & 7) << 4));
    };
    const char* kg0 = mksrc(kpB, 2048, o0);
    const char* kg1 = mksrc(kpB, 2048, o0 + 4096);
    const char* vg0 = mksrc(vTB, 16384, o0);
    const char* vg1 = mksrc(vTB, 16384, o0 + 4096);

    // prologue: tile 0 -> buf 0
    gload16(kg0, smem + w * 1024);
    gload16(kg1, smem + 4096 + w * 1024);
    gload16(vg0, smem + 16384 + w * 1024);
    gload16(vg1, smem + 16384 + 4096 + w * 1024);
    kg0 += 131072; kg1 += 131072; vg0 += 128; vg1 += 128;
    __syncthreads();

#define ATILE(CUR, PF)                                                          \
    {                                                                           \
        if (PF) {                                                               \
            gload16(kg0, smem + ((CUR) ^ 1) * 8192 + w * 1024);                 \
            gload16(kg1, smem + ((CUR) ^ 1) * 8192 + 4096 + w * 1024);          \
            gload16(vg0, smem + 16384 + ((CUR) ^ 1) * 8192 + w * 1024);         \
            gload16(vg1, smem + 16384 + ((CUR) ^ 1) * 8192 + 4096 + w * 1024);  \
            kg0 += 131072; kg1 += 131072; vg0 += 128; vg1 += 128;               \
        }                                                                       \
        f32x4 s0v = (f32x4)0.0f, s1v = (f32x4)0.0f;                             \
        f32x4 s2v = (f32x4)0.0f, s3v = (f32x4)0.0f;                             \
        {                                                                       \
            bf16x8 k0 = *(const bf16x8*)(smem + (CUR) * 8192 + 0 + kb0);        \
            bf16x8 k1 = *(const bf16x8*)(smem + (CUR) * 8192 + 2048 + kb0);     \
            bf16x8 k2 = *(const bf16x8*)(smem + (CUR) * 8192 + 4096 + kb0);     \
            bf16x8 k3 = *(const bf16x8*)(smem + (CUR) * 8192 + 6144 + kb0);     \
            s0v = MFMA16(k0, qf0, s0v); s1v = MFMA16(k1, qf0, s1v);             \
            s2v = MFMA16(k2, qf0, s2v); s3v = MFMA16(k3, qf0, s3v);             \
            k0 = *(const bf16x8*)(smem + (CUR) * 8192 + 0 + kb1);               \
            k1 = *(const bf16x8*)(smem + (CUR) * 8192 + 2048 + kb1);            \
            k2 = *(const bf16x8*)(smem + (CUR) * 8192 + 4096 + kb1);            \
            k3 = *(const bf16x8*)(smem + (CUR) * 8192 + 6144 + kb1);            \
            s0v = MFMA16(k0, qf1, s0v); s1v = MFMA16(k1, qf1, s1v);             \
            s2v = MFMA16(k2, qf1, s2v); s3v = MFMA16(k3, qf1, s3v);             \
        }                                                                       \
        float tm;                                                               \
        {                                                                       \
            float a0 = fmaxf(fmaxf(s0v[0], s0v[1]), fmaxf(s0v[2], s0v[3]));     \
            float a1 = fmaxf(fmaxf(s1v[0], s1v[1]), fmaxf(s1v[2], s1v[3]));     \
            float a2 = fmaxf(fmaxf(s2v[0], s2v[1]), fmaxf(s2v[2], s2v[3]));     \
            float a3 = fmaxf(fmaxf(s3v[0], s3v[1]), fmaxf(s3v[2], s3v[3]));     \
            tm = fmaxf(fmaxf(a0, a1), fmaxf(a2, a3));                           \
        }                                                                       \
        tm = fmaxf(tm, __shfl_xor(tm, 16));                                     \
        tm = fmaxf(tm, __shfl_xor(tm, 32));                                     \
        if (!__all(tm <= mrow + 8.0f)) {                                        \
            const float nm = fmaxf(mrow, tm);                                   \
            const float al = exp2f(mrow - nm);                                  \
            mrow = nm;                                                          \
            _Pragma("unroll")                                                   \
            for (int j = 0; j < 4; ++j) {                                       \
                const float alr = __shfl(al, g * 4 + j);                        \
                lacc[j] *= alr;                                                 \
                oacc[0][j] *= alr; oacc[1][j] *= alr;                           \
                oacc[2][j] *= alr; oacc[3][j] *= alr;                           \
            }                                                                   \
        }                                                                       \
        asm volatile("" ::: "memory");                                          \
        {                                                                       \
            float p0 = exp2f(s0v[0] - mrow), p1 = exp2f(s0v[1] - mrow);         \
            float p2 = exp2f(s0v[2] - mrow), p3 = exp2f(s0v[3] - mrow);         \
            *(unsigned long long*)(smem + pw0) =                                \
                ((unsigned long long)cvtpk(p2, p3) << 32) | cvtpk(p0, p1);      \
            p0 = exp2f(s1v[0] - mrow); p1 = exp2f(s1v[1] - mrow);               \
            p2 = exp2f(s1v[2] - mrow); p3 = exp2f(s1v[3] - mrow);               \
            *(unsigned long long*)(smem + pwm1) =                               \
                ((unsigned long long)cvtpk(p2, p3) << 32) | cvtpk(p0, p1);      \
            p0 = exp2f(s2v[0] - mrow); p1 = exp2f(s2v[1] - mrow);               \
            p2 = exp2f(s2v[2] - mrow); p3 = exp2f(s2v[3] - mrow);               \
            *(unsigned long long*)(smem + pwm2) =                               \
                ((unsigned long long)cvtpk(p2, p3) << 32) | cvtpk(p0, p1);      \
            p0 = exp2f(s3v[0] - mrow); p1 = exp2f(s3v[1] - mrow);               \
            p2 = exp2f(s3v[2] - mrow); p3 = exp2f(s3v[3] - mrow);               \
            *(unsigned long long*)(smem + pwm3) =                               \
                ((unsigned long long)cvtpk(p2, p3) << 32) | cvtpk(p0, p1);      \
        }                                                                       \
        asm volatile("s_waitcnt lgkmcnt(0)" ::: "memory");                      \
        __builtin_amdgcn_sched_barrier(0);                                      \
        {                                                                       \
            bf16x8 pa = *(const bf16x8*)(smem + pr0);                           \
            bf16x8 vb;                                                          \
            lacc = MFMA16(pa, ones, lacc);                                      \
            vb = *(const bf16x8*)(smem + 16384 + (CUR) * 8192 + 0 + kb0);       \
            oacc[0] = MFMA16(pa, vb, oacc[0]);                                  \
            vb = *(const bf16x8*)(smem + 16384 + (CUR) * 8192 + 2048 + kb0);    \
            oacc[1] = MFMA16(pa, vb, oacc[1]);                                  \
            vb = *(const bf16x8*)(smem + 16384 + (CUR) * 8192 + 4096 + kb0);    \
            oacc[2] = MFMA16(pa, vb, oacc[2]);                                  \
            vb = *(const bf16x8*)(smem + 16384 + (CUR) * 8192 + 6144 + kb0);    \
            oacc[3] = MFMA16(pa, vb, oacc[3]);                                  \
            pa = *(const bf16x8*)(smem + pr1);                                  \
            lacc = MFMA16(pa, ones, lacc);                                      \
            vb = *(const bf16x8*)(smem + 16384 + (CUR) * 8192 + 0 + kb1);       \
            oacc[0] = MFMA16(pa, vb, oacc[0]);                                  \
            vb = *(const bf16x8*)(smem + 16384 + (CUR) * 8192 + 2048 + kb1);    \
            oacc[1] = MFMA16(pa, vb, oacc[1]);                                  \
            vb = *(const bf16x8*)(smem + 16384 + (CUR) * 8192 + 4096 + kb1);    \
            oacc[2] = MFMA16(pa, vb, oacc[2]);                                  \
            vb = *(const bf16x8*)(smem + 16384 + (CUR) * 8192 + 6144 + kb1);    \
            oacc[3] = MFMA16(pa, vb, oacc[3]);                                  \
        }                                                                       \
        __builtin_amdgcn_sched_barrier(0);                                      \
        __syncthreads();                                                        \
    }

    for (int ti = 0; ti < 64; ti += 2) {
        ATILE(0, true)
        ATILE(1, ti < 62)
    }
#undef ATILE

    // epilogue: oacc rows are q = s0 + g*4 + j; lacc[j] is that row's denom
    const size_t obase = ((size_t)b * 2048 + s0 + g * 4) * 1024 + h * 64 + c;
#pragma unroll
    for (int j = 0; j < 4; ++j) {
        const float rinv = 1.0f / lacc[j];
#pragma unroll
        for (int df = 0; df < 4; ++df)
            out[obase + (size_t)j * 1024 + df * 16] = f2bf(oacc[df][j] * rinv);
    }
}

// ---------- gate + residual ----------
__global__ __launch_bounds__(256) void gate_out_k(
    const ushort* __restrict__ gs, const float* __restrict__ Wg2,
    const float* __restrict__ bg2, const float* __restrict__ query,
    const float* __restrict__ retr, float* __restrict__ out)
{
    const int r = blockIdx.x, t = threadIdx.x, w = t >> 6, l = t & 63;
    ushort4 gv = ((const ushort4*)(gs + (size_t)r * 1024))[t];
    float4 wv = ((const float4*)Wg2)[t];
    float p = bf2f(gv.x) * wv.x + bf2f(gv.y) * wv.y + bf2f(gv.z) * wv.z + bf2f(gv.w) * wv.w;
    for (int m = 1; m < 64; m <<= 1) p += __shfl_xor(p, m);
    __shared__ float red[4];
    if (l == 0) red[w] = p;
    __syncthreads();
    const float dot = red[0] + red[1] + red[2] + red[3] + bg2[0];
    const float gate = 1.0f / (1.0f + __expf(-dot));
    float4 q = ((const float4*)(query + (size_t)r * 1024))[t];
    float4 rt = ((const float4*)(retr + (size_t)r * 1024))[t];
    float4 o;
    o.x = q.x + gate * rt.x; o.y = q.y + gate * rt.y;
    o.z = q.z + gate * rt.z; o.w = q.w + gate * rt.w;
    ((float4*)(out + (size_t)r * 1024))[t] = o;
}

// ---------- launcher ----------
extern "C" void kernel_launch(void* const* d_in, const int* in_sizes, int n_in,
                              void* d_out, int out_size, void* d_ws, size_t ws_size,
                              hipStream_t stream) {
    const float* query = (const float*)d_in[0];   // 2x2048x1024
    const float* mkeys = (const float*)d_in[1];   // 2x4096x768
    const float* mvals = (const float*)d_in[2];   // 2x4096x768
    const float* Wq  = (const float*)d_in[3];
    const float* bq  = (const float*)d_in[4];
    const float* Wk  = (const float*)d_in[5];
    const float* bk  = (const float*)d_in[6];
    const float* Wv  = (const float*)d_in[7];
    const float* bv  = (const float*)d_in[8];
    const float* Wo  = (const float*)d_in[9];
    const float* bo  = (const float*)d_in[10];
    const float* Wg1 = (const float*)d_in[11];
    const float* bg1 = (const float*)d_in[12];
    const float* Wg2 = (const float*)d_in[13];
    const float* bg2 = (const float*)d_in[14];
    float* outF = (float*)d_out;

    char* ws = (char*)d_ws;
    size_t off = 0;
    auto take = [&](size_t bytes) { char* p = ws + off; off += (bytes + 255) & ~(size_t)255; return p; };
    ushort* cat    = (ushort*)take((size_t)4096 * 2048 * 2); // [query_bf | retro_bf]
    ushort* mkbf   = (ushort*)take((size_t)8192 * 768 * 2);
    ushort* mvbf   = (ushort*)take((size_t)8192 * 768 * 2);
    ushort* wqbf   = (ushort*)take((size_t)1024 * 1024 * 2);
    ushort* wkbf   = (ushort*)take((size_t)1024 * 768 * 2);
    ushort* wvbf   = (ushort*)take((size_t)1024 * 768 * 2);
    ushort* wobf   = (ushort*)take((size_t)1024 * 1024 * 2);
    ushort* wg1bf  = (ushort*)take((size_t)1024 * 2048 * 2);
    ushort* qproj  = (ushort*)take((size_t)4096 * 1024 * 2);
    ushort* kproj  = (ushort*)take((size_t)8192 * 1024 * 2);
    ushort* vprojT = (ushort*)take((size_t)1024 * 8192 * 2);
    ushort* attno  = (ushort*)take((size_t)4096 * 1024 * 2);
    float*  retro  = (float*)take((size_t)4096 * 1024 * 4);
    ushort* gsilu  = (ushort*)take((size_t)4096 * 1024 * 2);

    // conversions (3 launches)
    cvt_query_cat<<<4096, 256, 0, stream>>>(query, cat);
    cvt_kv<<<2048, 256, 0, stream>>>(mkeys, mkbf, mvals, mvbf, 8192 * 768 / 4);
    cvt_weights<<<1024, 256, 0, stream>>>(Wq, wqbf, 1024 * 1024 / 4,
                                          Wk, wkbf, 1024 * 768 / 4,
                                          Wv, wvbf, 1024 * 768 / 4,
                                          Wo, wobf, 1024 * 1024 / 4,
                                          Wg1, wg1bf, 1024 * 2048 / 4);

    // Q = (query Wq^T + bq) * Dh^-0.5 * log2(e)   [base-2 softmax domain]
    const float qscale = 0.125f * 1.44269504088896340736f;
    gemm_bt<0><<<dim3(16, 32), 256, 0, stream>>>(cat, 2048, wqbf, 1024, bq, qproj, 1024, nullptr, 1024, qscale);
    // K = mk Wk^T + bk
    gemm_bt<0><<<dim3(16, 64), 256, 0, stream>>>(mkbf, 768, wkbf, 768, bk, kproj, 1024, nullptr, 768, 1.0f);
    // V^T = (mv Wv^T + bv)^T
    gemm_bt<1><<<dim3(16, 64), 256, 0, stream>>>(mvbf, 768, wvbf, 768, bv, vprojT, 8192, nullptr, 768, 1.0f);
    // attention
    attn_fwd<<<dim3(32, 16, 2), 256, 0, stream>>>(qproj, kproj, vprojT, attno);
    // retr_o = attn_out Wo^T + bo  -> f32 (residual) + bf16 into cat cols 1024..2047
    gemm_bt<2><<<dim3(16, 32), 256, 0, stream>>>(attno, 1024, wobf, 1024, bo, cat + 1024, 1024, retro, 1024, 1.0f);
    // g = silu([query; retr_o] Wg1^T + bg1)
    gemm_bt<3><<<dim3(16, 32), 256, 0, stream>>>(cat, 2048, wg1bf, 2048, bg1, gsilu, 1024, nullptr, 2048, 1.0f);
    // gate + residual
    gate_out_k<<<4096, 256, 0, stream>>>(gsilu, Wg2, bg2, query, retro, outF);
}

// Round 5
// 398.039 us; speedup vs baseline: 1.0192x; 1.0192x over previous
//
#include <hip/hip_runtime.h>

// ---------- types ----------
typedef __attribute__((ext_vector_type(8))) __bf16 bf16x8;   // MFMA A/B frag (4 VGPR)
typedef __attribute__((ext_vector_type(4))) float f32x4;     // MFMA C/D frag
typedef __attribute__((ext_vector_type(8))) unsigned short u16x8;

// fp32 -> bf16 (RNE, no NaN inputs expected)
__device__ __forceinline__ ushort f2bf(float x) {
    unsigned u = __builtin_bit_cast(unsigned, x);
    unsigned r = u + 0x7fffu + ((u >> 16) & 1u);
    return (ushort)(r >> 16);
}
__device__ __forceinline__ float bf2f(ushort u) {
    unsigned v = ((unsigned)u) << 16;
    return __builtin_bit_cast(float, v);
}

// packed f32x2 -> bf16x2 (T12)
__device__ __forceinline__ unsigned cvtpk(float lo, float hi) {
    unsigned r;
    asm("v_cvt_pk_bf16_f32 %0, %1, %2" : "=v"(r) : "v"(lo), "v"(hi));
    return r;
}

// async global->LDS, 16B per lane. LDS dest = wave-uniform base + lane*16.
__device__ __forceinline__ void gload16(const void* g, void* l) {
    __builtin_amdgcn_global_load_lds(
        (const __attribute__((address_space(1))) void*)g,
        (__attribute__((address_space(3))) void*)l,
        16, 0, 0);
}

#define MFMA16(a, b, cIn) __builtin_amdgcn_mfma_f32_16x16x32_bf16((a), (b), (cIn), 0, 0, 0)

// ---------- conversion kernels (fused launches) ----------
__global__ __launch_bounds__(256) void cvt_kv(const float* __restrict__ a, ushort* __restrict__ ab,
                                              const float* __restrict__ bsrc, ushort* __restrict__ bb,
                                              int n4) {
    const int stride = gridDim.x * 256;
    for (int i = blockIdx.x * 256 + threadIdx.x; i < n4; i += stride) {
        float4 v = ((const float4*)a)[i];
        ushort4 o; o.x = f2bf(v.x); o.y = f2bf(v.y); o.z = f2bf(v.z); o.w = f2bf(v.w);
        ((ushort4*)ab)[i] = o;
    }
    for (int i = blockIdx.x * 256 + threadIdx.x; i < n4; i += stride) {
        float4 v = ((const float4*)bsrc)[i];
        ushort4 o; o.x = f2bf(v.x); o.y = f2bf(v.y); o.z = f2bf(v.z); o.w = f2bf(v.w);
        ((ushort4*)bb)[i] = o;
    }
}

__global__ __launch_bounds__(256) void cvt_weights(
    const float* __restrict__ s0, ushort* __restrict__ d0, int n0,
    const float* __restrict__ s1, ushort* __restrict__ d1, int n1,
    const float* __restrict__ s2, ushort* __restrict__ d2, int n2,
    const float* __restrict__ s3, ushort* __restrict__ d3, int n3,
    const float* __restrict__ s4, ushort* __restrict__ d4, int n4c) {
    const int stride = gridDim.x * 256;
    const int t0 = blockIdx.x * 256 + threadIdx.x;
#define CVT_SEG(S, D, N)                                                  \
    for (int i = t0; i < (N); i += stride) {                              \
        float4 v = ((const float4*)(S))[i];                               \
        ushort4 o; o.x = f2bf(v.x); o.y = f2bf(v.y);                      \
        o.z = f2bf(v.z); o.w = f2bf(v.w);                                 \
        ((ushort4*)(D))[i] = o;                                           \
    }
    CVT_SEG(s0, d0, n0) CVT_SEG(s1, d1, n1) CVT_SEG(s2, d2, n2)
    CVT_SEG(s3, d3, n3) CVT_SEG(s4, d4, n4c)
#undef CVT_SEG
}

// query (4096x1024 f32) -> cat buffer cols 0..1023 (row stride 2048, bf16)
__global__ __launch_bounds__(256) void cvt_query_cat(const float* __restrict__ in,
                                                     ushort* __restrict__ cat) {
    const int r = blockIdx.x, t = threadIdx.x;
    float4 v = ((const float4*)(in + (size_t)r * 1024))[t];
    ushort4 o;
    o.x = f2bf(v.x); o.y = f2bf(v.y); o.z = f2bf(v.z); o.w = f2bf(v.w);
    ((ushort4*)(cat + (size_t)r * 2048))[t] = o;
}

// ---------- GEMM: C = A(MxK,bf16) @ W(NxK,bf16)^T + bias ----------
// 128M x 64N x 64K tiles, 4 waves (2x2), wave tile 64x32, acc 4x2.
// 3-slot LDS ring, counted vmcnt(6) (never 0 mid-loop), ONE raw barrier/iter.
// WAR safety: slot (t+2)%3 staged at iter t was last read at iter t-1, sealed
// by that iter's barrier (reads retire before the barrier since every ds_read
// is consumed by an MFMA issued before it).
template<int EPI>
__global__ __launch_bounds__(256, 2) void gemm_bt(
    const ushort* __restrict__ A, int lda,
    const ushort* __restrict__ Bw, int ldb,
    const float* __restrict__ bias,
    ushort* __restrict__ o_bf, int ld0,
    float* __restrict__ o_f32,
    int K, float scale)
{
    __shared__ __align__(1024) char smem[73728];  // A: 3x16K @0; B: 3x8K @49152
    const int t = threadIdx.x, w = t >> 6, l = t & 63, g = l >> 4, c = l & 15;
    const int wr = w >> 1, wc = w & 1;
    const long m0 = (long)blockIdx.y * 128, n0 = (long)blockIdx.x * 64;
    const size_t ldaB = (size_t)lda * 2, ldbB = (size_t)ldb * 2;
    const int swz = (c & 7) << 4;
    const int o0 = w * 1024 + l * 16;

    auto gsrc = [&](const char* base, size_t ldB, long r0, int o) {
        const int row = o >> 7, cb = o & 127;
        return base + (size_t)(r0 + row) * ldB + (cb ^ ((row & 7) << 4));
    };
    const char* aP0 = gsrc((const char*)A, ldaB, m0, o0);
    const char* aP1 = gsrc((const char*)A, ldaB, m0, o0 + 4096);
    const char* aP2 = gsrc((const char*)A, ldaB, m0, o0 + 8192);
    const char* aP3 = gsrc((const char*)A, ldaB, m0, o0 + 12288);
    const char* bP0 = gsrc((const char*)Bw, ldbB, n0, o0);
    const char* bP1 = gsrc((const char*)Bw, ldbB, n0, o0 + 4096);

    // LDS read bases within a slot (XOR identity: kf flips bit 6)
    const int aRd0 = (wr * 64 + c) * 128 + ((g * 16) ^ swz);
    const int aRd1 = aRd0 ^ 64;
    const int bRd0 = (wc * 32 + c) * 128 + ((g * 16) ^ swz);
    const int bRd1 = bRd0 ^ 64;

    f32x4 acc[4][2];
#pragma unroll
    for (int i = 0; i < 4; ++i)
#pragma unroll
        for (int j = 0; j < 2; ++j) acc[i][j] = (f32x4)0.0f;

    auto stage = [&](int slotA) {
        gload16(aP0, smem + slotA + w * 1024);
        gload16(aP1, smem + slotA + 4096 + w * 1024);
        gload16(aP2, smem + slotA + 8192 + w * 1024);
        gload16(aP3, smem + slotA + 12288 + w * 1024);
        gload16(bP0, smem + 49152 + (slotA >> 1) + w * 1024);
        gload16(bP1, smem + 49152 + (slotA >> 1) + 4096 + w * 1024);
        aP0 += 128; aP1 += 128; aP2 += 128; aP3 += 128;
        bP0 += 128; bP1 += 128;
    };

    const int nkt = K >> 6;
    // prologue: tiles 0,1 -> slots 0,1 (12 loads); wait 6 oldest -> slot0 ready
    stage(0);
    stage(16384);
    asm volatile("s_waitcnt vmcnt(6)" ::: "memory");
    __builtin_amdgcn_s_barrier();

    int rdA = 0, stA = 32768;
    for (int kt = 0; kt < nkt; ++kt) {
        const bool pf = (kt + 2 < nkt);
        if (pf) {
            stage(stA);
            stA = (stA == 32768) ? 0 : stA + 16384;
        }
        const char* Ac = smem + rdA;
        const char* Bc = smem + 49152 + (rdA >> 1);
#pragma unroll
        for (int kf = 0; kf < 2; ++kf) {
            const int ar = kf ? aRd1 : aRd0, br = kf ? bRd1 : bRd0;
            bf16x8 af0 = *(const bf16x8*)(Ac + 0 + ar);
            bf16x8 af1 = *(const bf16x8*)(Ac + 2048 + ar);
            bf16x8 af2 = *(const bf16x8*)(Ac + 4096 + ar);
            bf16x8 af3 = *(const bf16x8*)(Ac + 6144 + ar);
            bf16x8 bf0 = *(const bf16x8*)(Bc + 0 + br);
            bf16x8 bf1 = *(const bf16x8*)(Bc + 2048 + br);
            acc[0][0] = MFMA16(af0, bf0, acc[0][0]);
            acc[0][1] = MFMA16(af0, bf1, acc[0][1]);
            acc[1][0] = MFMA16(af1, bf0, acc[1][0]);
            acc[1][1] = MFMA16(af1, bf1, acc[1][1]);
            acc[2][0] = MFMA16(af2, bf0, acc[2][0]);
            acc[2][1] = MFMA16(af2, bf1, acc[2][1]);
            acc[3][0] = MFMA16(af3, bf0, acc[3][0]);
            acc[3][1] = MFMA16(af3, bf1, acc[3][1]);
        }
        rdA = (rdA == 32768) ? 0 : rdA + 16384;
        if (pf) asm volatile("s_waitcnt vmcnt(6)" ::: "memory");
        else    asm volatile("s_waitcnt vmcnt(0)" ::: "memory");
        __builtin_amdgcn_s_barrier();
    }

    // epilogue: C/D layout col = l&15, row = (l>>4)*4 + jj  [verified m89/m91]
#pragma unroll
    for (int i = 0; i < 4; ++i)
#pragma unroll
        for (int j = 0; j < 2; ++j) {
            const long col = n0 + wc * 32 + j * 16 + c;
            const float bs = bias[col];
            const long rowb = m0 + wr * 64 + i * 16 + g * 4;
            if (EPI == 1) {
                ushort4 o;
                o.x = f2bf(acc[i][j][0] + bs);
                o.y = f2bf(acc[i][j][1] + bs);
                o.z = f2bf(acc[i][j][2] + bs);
                o.w = f2bf(acc[i][j][3] + bs);
                *(ushort4*)(o_bf + col * (long)ld0 + rowb) = o;
            } else {
#pragma unroll
                for (int jj = 0; jj < 4; ++jj) {
                    const long row = rowb + jj;
                    const float v = acc[i][j][jj] + bs;
                    if (EPI == 0) {
                        o_bf[row * (long)ld0 + col] = f2bf(v * scale);
                    } else if (EPI == 2) {
                        o_f32[row * (long)ld0 + col] = v;
                        o_bf[row * 2048 + col] = f2bf(v);
                    } else { // EPI == 3 : silu
                        const float sv = v / (1.0f + __expf(-v));
                        o_bf[row * (long)ld0 + col] = f2bf(sv);
                    }
                }
            }
        }
}

// ---------- flash attention: 32 q-rows/wave, 3-slot ring, counted vmcnt ----------
// grid (S/128, H, B), 256 threads = 4 waves; wave owns 32 q-rows (2 groups of 16);
// block covers 128 q-rows; KVBLK=64. K/V fragments read ONCE per wave, used for
// both q-groups (halves the per-CU LDS read traffic vs 16 rows/wave).
// qp PRE-SCALED by Dh^-0.5*log2(e); vT: 1024x(B*M) bf16 (transposed V).
// Lane (c,g) owns P[q=s0(+16)+c][k=mf*16+g*4+j]; denominator via ones-MFMA.
__global__ __launch_bounds__(256, 2) void attn_fwd(
    const ushort* __restrict__ qp, const ushort* __restrict__ kp,
    const ushort* __restrict__ vT, ushort* __restrict__ out)
{
    __shared__ __align__(1024) char smem[65536];
    // K slots: 3x8KB @0; V slots: 3x8KB @24576; P: 4 x [32 rows][128B] @49152
    const int t = threadIdx.x, w = t >> 6, l = t & 63, g = l >> 4, c = l & 15;
    const int b = blockIdx.z, h = blockIdx.y;
    const int s0 = blockIdx.x * 128 + w * 32;
    const int swz = (c & 7) << 4;

    const size_t qbaseA = ((size_t)b * 2048 + s0 + c) * 1024 + h * 64 + g * 8;
    const bf16x8 qA0 = *(const bf16x8*)(qp + qbaseA);
    const bf16x8 qA1 = *(const bf16x8*)(qp + qbaseA + 32);
    const bf16x8 qB0 = *(const bf16x8*)(qp + qbaseA + 16 * 1024);
    const bf16x8 qB1 = *(const bf16x8*)(qp + qbaseA + 16 * 1024 + 32);

    const u16x8 ones_u = (u16x8)(ushort)0x3F80;           // bf16 1.0 x8
    const bf16x8 ones = __builtin_bit_cast(bf16x8, ones_u);

    f32x4 oaccA[4], oaccB[4];
    f32x4 laccA = (f32x4)0.0f, laccB = (f32x4)0.0f;
#pragma unroll
    for (int d = 0; d < 4; ++d) { oaccA[d] = (f32x4)0.0f; oaccB[d] = (f32x4)0.0f; }
    float mrowA = -1e30f, mrowB = -1e30f;

    // LDS bases (within a slot); XOR identities as before
    const int kb0 = c * 128 + ((g * 16) ^ swz);
    const int kb1 = kb0 ^ 64;
    const int Pbase = 49152 + w * 4096;       // [32 rows][128B]: rows 0-15 = A, 16-31 = B
    const int pw0 = Pbase + c * 128 + ((g * 8) ^ swz);
    const int pr0 = Pbase + kb0;
    const int pr1 = pr0 ^ 64;

    // global stage pointers (advance: K +131072 B, V +128 B per tile)
    const char* kpB = (const char*)kp + (size_t)b * 4096 * 2048 + h * 128;
    const char* vTB = (const char*)vT + (size_t)h * 64 * 16384 + (size_t)b * 4096 * 2;
    const int o0 = w * 1024 + l * 16;
    auto mksrc = [&](const char* base, size_t ldB, int o) {
        const int row = o >> 7, cb = o & 127;
        return base + (size_t)row * ldB + (cb ^ ((row & 7) << 4));
    };
    const char* kg0 = mksrc(kpB, 2048, o0);
    const char* kg1 = mksrc(kpB, 2048, o0 + 4096);
    const char* vg0 = mksrc(vTB, 16384, o0);
    const char* vg1 = mksrc(vTB, 16384, o0 + 4096);

    auto stage = [&](int stK) {
        gload16(kg0, smem + stK + w * 1024);
        gload16(kg1, smem + stK + 4096 + w * 1024);
        gload16(vg0, smem + 24576 + stK + w * 1024);
        gload16(vg1, smem + 24576 + stK + 4096 + w * 1024);
        kg0 += 131072; kg1 += 131072; vg0 += 128; vg1 += 128;
    };

    // prologue: tiles 0,1 -> slots 0,1 (8 loads); wait 4 oldest -> slot0 ready
    stage(0);
    stage(8192);
    asm volatile("s_waitcnt vmcnt(4)" ::: "memory");
    __builtin_amdgcn_s_barrier();

    int rdK = 0, stK = 16384;
    for (int ti = 0; ti < 64; ++ti) {
        const bool pf = (ti < 62);
        if (pf) {
            stage(stK);
            stK = (stK == 16384) ? 0 : stK + 8192;
        }
        const char* Ksc = smem + rdK;
        const char* Vsc = smem + 24576 + rdK;

        // S^T = K Q^T for both q-groups; K frags read once
        f32x4 sA[4], sB[4];
#pragma unroll
        for (int mf = 0; mf < 4; ++mf) { sA[mf] = (f32x4)0.0f; sB[mf] = (f32x4)0.0f; }
#pragma unroll
        for (int kf = 0; kf < 2; ++kf) {
            const int kbase = kf ? kb1 : kb0;
            const bf16x8 qa = kf ? qA1 : qA0;
            const bf16x8 qb = kf ? qB1 : qB0;
#pragma unroll
            for (int mf = 0; mf < 4; ++mf) {
                const bf16x8 kb = *(const bf16x8*)(Ksc + mf * 2048 + kbase);
                sA[mf] = MFMA16(kb, qa, sA[mf]);
                sB[mf] = MFMA16(kb, qb, sB[mf]);
            }
        }

        // ---- softmax group A ----
        float tmA;
        {
            float a0 = fmaxf(fmaxf(sA[0][0], sA[0][1]), fmaxf(sA[0][2], sA[0][3]));
            float a1 = fmaxf(fmaxf(sA[1][0], sA[1][1]), fmaxf(sA[1][2], sA[1][3]));
            float a2 = fmaxf(fmaxf(sA[2][0], sA[2][1]), fmaxf(sA[2][2], sA[2][3]));
            float a3 = fmaxf(fmaxf(sA[3][0], sA[3][1]), fmaxf(sA[3][2], sA[3][3]));
            tmA = fmaxf(fmaxf(a0, a1), fmaxf(a2, a3));
        }
        tmA = fmaxf(tmA, __shfl_xor(tmA, 16));
        tmA = fmaxf(tmA, __shfl_xor(tmA, 32));
        if (!__all(tmA <= mrowA + 8.0f)) {
            const float nm = fmaxf(mrowA, tmA);
            const float al = exp2f(mrowA - nm);
            mrowA = nm;
#pragma unroll
            for (int j = 0; j < 4; ++j) {
                const float alr = __shfl(al, g * 4 + j);
                laccA[j] *= alr;
                oaccA[0][j] *= alr; oaccA[1][j] *= alr;
                oaccA[2][j] *= alr; oaccA[3][j] *= alr;
            }
        }
        // ---- softmax group B ----
        float tmB;
        {
            float a0 = fmaxf(fmaxf(sB[0][0], sB[0][1]), fmaxf(sB[0][2], sB[0][3]));
            float a1 = fmaxf(fmaxf(sB[1][0], sB[1][1]), fmaxf(sB[1][2], sB[1][3]));
            float a2 = fmaxf(fmaxf(sB[2][0], sB[2][1]), fmaxf(sB[2][2], sB[2][3]));
            float a3 = fmaxf(fmaxf(sB[3][0], sB[3][1]), fmaxf(sB[3][2], sB[3][3]));
            tmB = fmaxf(fmaxf(a0, a1), fmaxf(a2, a3));
        }
        tmB = fmaxf(tmB, __shfl_xor(tmB, 16));
        tmB = fmaxf(tmB, __shfl_xor(tmB, 32));
        if (!__all(tmB <= mrowB + 8.0f)) {
            const float nm = fmaxf(mrowB, tmB);
            const float al = exp2f(mrowB - nm);
            mrowB = nm;
#pragma unroll
            for (int j = 0; j < 4; ++j) {
                const float alr = __shfl(al, g * 4 + j);
                laccB[j] *= alr;
                oaccB[0][j] *= alr; oaccB[1][j] *= alr;
                oaccB[2][j] *= alr; oaccB[3][j] *= alr;
            }
        }

        // exp + pack P (both groups), then PV with V frags read once
        asm volatile("" ::: "memory");   // keep prior-tile P reads before these writes
#pragma unroll
        for (int mf = 0; mf < 4; ++mf) {
            {
                const float p0 = exp2f(sA[mf][0] - mrowA);
                const float p1 = exp2f(sA[mf][1] - mrowA);
                const float p2 = exp2f(sA[mf][2] - mrowA);
                const float p3 = exp2f(sA[mf][3] - mrowA);
                *(unsigned long long*)(smem + (pw0 ^ (mf * 32))) =
                    ((unsigned long long)cvtpk(p2, p3) << 32) | cvtpk(p0, p1);
            }
            {
                const float p0 = exp2f(sB[mf][0] - mrowB);
                const float p1 = exp2f(sB[mf][1] - mrowB);
                const float p2 = exp2f(sB[mf][2] - mrowB);
                const float p3 = exp2f(sB[mf][3] - mrowB);
                *(unsigned long long*)(smem + 2048 + (pw0 ^ (mf * 32))) =
                    ((unsigned long long)cvtpk(p2, p3) << 32) | cvtpk(p0, p1);
            }
        }
        asm volatile("s_waitcnt lgkmcnt(0)" ::: "memory");
        __builtin_amdgcn_sched_barrier(0);
#pragma unroll
        for (int km = 0; km < 2; ++km) {
            const int prk = km ? pr1 : pr0;
            const int vbase = km ? kb1 : kb0;
            const bf16x8 paA = *(const bf16x8*)(smem + prk);
            const bf16x8 paB = *(const bf16x8*)(smem + 2048 + prk);
            laccA = MFMA16(paA, ones, laccA);
            laccB = MFMA16(paB, ones, laccB);
#pragma unroll
            for (int df = 0; df < 4; ++df) {
                const bf16x8 vb = *(const bf16x8*)(Vsc + df * 2048 + vbase);
                oaccA[df] = MFMA16(paA, vb, oaccA[df]);
                oaccB[df] = MFMA16(paB, vb, oaccB[df]);
            }
        }
        __builtin_amdgcn_sched_barrier(0);
        rdK = (rdK == 16384) ? 0 : rdK + 8192;
        if (pf) asm volatile("s_waitcnt vmcnt(4)" ::: "memory");
        else    asm volatile("s_waitcnt vmcnt(0)" ::: "memory");
        __builtin_amdgcn_s_barrier();
    }

    // epilogue: oacc rows are q = s0 (+16) + g*4 + j; lacc[j] is that row's denom
    const size_t obase = ((size_t)b * 2048 + s0 + g * 4) * 1024 + h * 64 + c;
#pragma unroll
    for (int j = 0; j < 4; ++j) {
        const float rinvA = 1.0f / laccA[j];
        const float rinvB = 1.0f / laccB[j];
#pragma unroll
        for (int df = 0; df < 4; ++df) {
            out[obase + (size_t)j * 1024 + df * 16] = f2bf(oaccA[df][j] * rinvA);
            out[obase + (size_t)(j + 16) * 1024 + df * 16] = f2bf(oaccB[df][j] * rinvB);
        }
    }
}

// ---------- gate + residual ----------
__global__ __launch_bounds__(256) void gate_out_k(
    const ushort* __restrict__ gs, const float* __restrict__ Wg2,
    const float* __restrict__ bg2, const float* __restrict__ query,
    const float* __restrict__ retr, float* __restrict__ out)
{
    const int r = blockIdx.x, t = threadIdx.x, w = t >> 6, l = t & 63;
    ushort4 gv = ((const ushort4*)(gs + (size_t)r * 1024))[t];
    float4 wv = ((const float4*)Wg2)[t];
    float p = bf2f(gv.x) * wv.x + bf2f(gv.y) * wv.y + bf2f(gv.z) * wv.z + bf2f(gv.w) * wv.w;
    for (int m = 1; m < 64; m <<= 1) p += __shfl_xor(p, m);
    __shared__ float red[4];
    if (l == 0) red[w] = p;
    __syncthreads();
    const float dot = red[0] + red[1] + red[2] + red[3] + bg2[0];
    const float gate = 1.0f / (1.0f + __expf(-dot));
    float4 q = ((const float4*)(query + (size_t)r * 1024))[t];
    float4 rt = ((const float4*)(retr + (size_t)r * 1024))[t];
    float4 o;
    o.x = q.x + gate * rt.x; o.y = q.y + gate * rt.y;
    o.z = q.z + gate * rt.z; o.w = q.w + gate * rt.w;
    ((float4*)(out + (size_t)r * 1024))[t] = o;
}

// ---------- launcher ----------
extern "C" void kernel_launch(void* const* d_in, const int* in_sizes, int n_in,
                              void* d_out, int out_size, void* d_ws, size_t ws_size,
                              hipStream_t stream) {
    const float* query = (const float*)d_in[0];   // 2x2048x1024
    const float* mkeys = (const float*)d_in[1];   // 2x4096x768
    const float* mvals = (const float*)d_in[2];   // 2x4096x768
    const float* Wq  = (const float*)d_in[3];
    const float* bq  = (const float*)d_in[4];
    const float* Wk  = (const float*)d_in[5];
    const float* bk  = (const float*)d_in[6];
    const float* Wv  = (const float*)d_in[7];
    const float* bv  = (const float*)d_in[8];
    const float* Wo  = (const float*)d_in[9];
    const float* bo  = (const float*)d_in[10];
    const float* Wg1 = (const float*)d_in[11];
    const float* bg1 = (const float*)d_in[12];
    const float* Wg2 = (const float*)d_in[13];
    const float* bg2 = (const float*)d_in[14];
    float* outF = (float*)d_out;

    char* ws = (char*)d_ws;
    size_t off = 0;
    auto take = [&](size_t bytes) { char* p = ws + off; off += (bytes + 255) & ~(size_t)255; return p; };
    ushort* cat    = (ushort*)take((size_t)4096 * 2048 * 2); // [query_bf | retro_bf]
    ushort* mkbf   = (ushort*)take((size_t)8192 * 768 * 2);
    ushort* mvbf   = (ushort*)take((size_t)8192 * 768 * 2);
    ushort* wqbf   = (ushort*)take((size_t)1024 * 1024 * 2);
    ushort* wkbf   = (ushort*)take((size_t)1024 * 768 * 2);
    ushort* wvbf   = (ushort*)take((size_t)1024 * 768 * 2);
    ushort* wobf   = (ushort*)take((size_t)1024 * 1024 * 2);
    ushort* wg1bf  = (ushort*)take((size_t)1024 * 2048 * 2);
    ushort* qproj  = (ushort*)take((size_t)4096 * 1024 * 2);
    ushort* kproj  = (ushort*)take((size_t)8192 * 1024 * 2);
    ushort* vprojT = (ushort*)take((size_t)1024 * 8192 * 2);
    ushort* attno  = (ushort*)take((size_t)4096 * 1024 * 2);
    float*  retro  = (float*)take((size_t)4096 * 1024 * 4);
    ushort* gsilu  = (ushort*)take((size_t)4096 * 1024 * 2);

    // conversions (3 launches)
    cvt_query_cat<<<4096, 256, 0, stream>>>(query, cat);
    cvt_kv<<<2048, 256, 0, stream>>>(mkeys, mkbf, mvals, mvbf, 8192 * 768 / 4);
    cvt_weights<<<1024, 256, 0, stream>>>(Wq, wqbf, 1024 * 1024 / 4,
                                          Wk, wkbf, 1024 * 768 / 4,
                                          Wv, wvbf, 1024 * 768 / 4,
                                          Wo, wobf, 1024 * 1024 / 4,
                                          Wg1, wg1bf, 1024 * 2048 / 4);

    // Q = (query Wq^T + bq) * Dh^-0.5 * log2(e)   [base-2 softmax domain]
    const float qscale = 0.125f * 1.44269504088896340736f;
    gemm_bt<0><<<dim3(16, 32), 256, 0, stream>>>(cat, 2048, wqbf, 1024, bq, qproj, 1024, nullptr, 1024, qscale);
    // K = mk Wk^T + bk
    gemm_bt<0><<<dim3(16, 64), 256, 0, stream>>>(mkbf, 768, wkbf, 768, bk, kproj, 1024, nullptr, 768, 1.0f);
    // V^T = (mv Wv^T + bv)^T
    gemm_bt<1><<<dim3(16, 64), 256, 0, stream>>>(mvbf, 768, wvbf, 768, bv, vprojT, 8192, nullptr, 768, 1.0f);
    // attention
    attn_fwd<<<dim3(16, 16, 2), 256, 0, stream>>>(qproj, kproj, vprojT, attno);
    // retr_o = attn_out Wo^T + bo  -> f32 (residual) + bf16 into cat cols 1024..2047
    gemm_bt<2><<<dim3(16, 32), 256, 0, stream>>>(attno, 1024, wobf, 1024, bo, cat + 1024, 1024, retro, 1024, 1.0f);
    // g = silu([query; retr_o] Wg1^T + bg1)
    gemm_bt<3><<<dim3(16, 32), 256, 0, stream>>>(cat, 2048, wg1bf, 2048, bg1, gsilu, 1024, nullptr, 2048, 1.0f);
    // gate + residual
    gate_out_k<<<4096, 256, 0, stream>>>(gsilu, Wg2, bg2, query, retro, outF);
}

// Round 6
// 369.791 us; speedup vs baseline: 1.0971x; 1.0764x over previous
//
#include <hip/hip_runtime.h>

// ---------- types ----------
typedef __attribute__((ext_vector_type(8))) __bf16 bf16x8;    // MFMA A/B frag (4 VGPR)
typedef __attribute__((ext_vector_type(4))) float f32x4;      // 16x16 C/D frag
typedef __attribute__((ext_vector_type(16))) float f32x16;    // 32x32 C/D frag
typedef __attribute__((ext_vector_type(8))) unsigned short u16x8;
typedef __attribute__((ext_vector_type(4))) unsigned u32x4;

// fp32 -> bf16 (RNE)
__device__ __forceinline__ ushort f2bf(float x) {
    unsigned u = __builtin_bit_cast(unsigned, x);
    unsigned r = u + 0x7fffu + ((u >> 16) & 1u);
    return (ushort)(r >> 16);
}
__device__ __forceinline__ float bf2f(ushort u) {
    unsigned v = ((unsigned)u) << 16;
    return __builtin_bit_cast(float, v);
}

// packed f32x2 -> bf16x2 (T12)
__device__ __forceinline__ unsigned cvtpk(float lo, float hi) {
    unsigned r;
    asm("v_cvt_pk_bf16_f32 %0, %1, %2" : "=v"(r) : "v"(lo), "v"(hi));
    return r;
}

// async global->LDS, 16B/lane; LDS dest = wave-uniform base + lane*16
__device__ __forceinline__ void gload16(const void* g, void* l) {
    __builtin_amdgcn_global_load_lds(
        (const __attribute__((address_space(1))) void*)g,
        (__attribute__((address_space(3))) void*)l,
        16, 0, 0);
}

#define MFMA16(a, b, cIn) __builtin_amdgcn_mfma_f32_16x16x32_bf16((a), (b), (cIn), 0, 0, 0)
#define MFMA32(a, b, cIn) __builtin_amdgcn_mfma_f32_32x32x16_bf16((a), (b), (cIn), 0, 0, 0)

// T12 lane exchange: build PV A-frag from packed P words (no LDS bounce).
// In: ua=pk(p0,p1) ub=pk(p2,p3) uc=pk(p4,p5) ud=pk(p6,p7) of one half-S-tile.
// permlane32_swap: v0[32+i] <-> v1[i]  =>  frag words [x1,x2,y1,y2] give
// hi=0: [own a, own b, partner a, partner b]; hi=1: [partner c, partner d, own c, own d]
__device__ __forceinline__ bf16x8 pv_frag(unsigned ua, unsigned ub, unsigned uc, unsigned ud) {
    unsigned x1 = ua, y1 = uc, x2 = ub, y2 = ud;
    asm("v_permlane32_swap_b32 %0, %1" : "+v"(x1), "+v"(y1));
    asm("v_permlane32_swap_b32 %0, %1" : "+v"(x2), "+v"(y2));
    u32x4 wv; wv[0] = x1; wv[1] = x2; wv[2] = y1; wv[3] = y2;
    return __builtin_bit_cast(bf16x8, wv);
}

// ---------- conversion kernels ----------
__global__ __launch_bounds__(256) void cvt_kv(const float* __restrict__ a, ushort* __restrict__ ab,
                                              const float* __restrict__ bsrc, ushort* __restrict__ bb,
                                              int n4) {
    const int stride = gridDim.x * 256;
    for (int i = blockIdx.x * 256 + threadIdx.x; i < n4; i += stride) {
        float4 v = ((const float4*)a)[i];
        ushort4 o; o.x = f2bf(v.x); o.y = f2bf(v.y); o.z = f2bf(v.z); o.w = f2bf(v.w);
        ((ushort4*)ab)[i] = o;
    }
    for (int i = blockIdx.x * 256 + threadIdx.x; i < n4; i += stride) {
        float4 v = ((const float4*)bsrc)[i];
        ushort4 o; o.x = f2bf(v.x); o.y = f2bf(v.y); o.z = f2bf(v.z); o.w = f2bf(v.w);
        ((ushort4*)bb)[i] = o;
    }
}

__global__ __launch_bounds__(256) void cvt_weights(
    const float* __restrict__ s0, ushort* __restrict__ d0, int n0,
    const float* __restrict__ s1, ushort* __restrict__ d1, int n1,
    const float* __restrict__ s2, ushort* __restrict__ d2, int n2,
    const float* __restrict__ s3, ushort* __restrict__ d3, int n3,
    const float* __restrict__ s4, ushort* __restrict__ d4, int n4c) {
    const int stride = gridDim.x * 256;
    const int t0 = blockIdx.x * 256 + threadIdx.x;
#define CVT_SEG(S, D, N)                                                  \
    for (int i = t0; i < (N); i += stride) {                              \
        float4 v = ((const float4*)(S))[i];                               \
        ushort4 o; o.x = f2bf(v.x); o.y = f2bf(v.y);                      \
        o.z = f2bf(v.z); o.w = f2bf(v.w);                                 \
        ((ushort4*)(D))[i] = o;                                           \
    }
    CVT_SEG(s0, d0, n0) CVT_SEG(s1, d1, n1) CVT_SEG(s2, d2, n2)
    CVT_SEG(s3, d3, n3) CVT_SEG(s4, d4, n4c)
#undef CVT_SEG
}

__global__ __launch_bounds__(256) void cvt_query_cat(const float* __restrict__ in,
                                                     ushort* __restrict__ cat) {
    const int r = blockIdx.x, t = threadIdx.x;
    float4 v = ((const float4*)(in + (size_t)r * 1024))[t];
    ushort4 o;
    o.x = f2bf(v.x); o.y = f2bf(v.y); o.z = f2bf(v.z); o.w = f2bf(v.w);
    ((ushort4*)(cat + (size_t)r * 2048))[t] = o;
}

// ---------- GEMM: C = A(MxK,bf16) @ W(NxK,bf16)^T + bias ----------
// 128x128x64 tiles, 4 waves (2x2), wave tile 64x64, acc 4x4 (m97-proven blocking:
// 8 LDS frag reads feed 16 MFMA per kf -> 0.5 reads/MFMA). 2-slot dbuf, counted
// vmcnt(8) (loads stay in flight across barrier), 2 barriers/iter (WAR seal).
template<int EPI>
__global__ __launch_bounds__(256, 2) void gemm_bt(
    const ushort* __restrict__ A, int lda,
    const ushort* __restrict__ Bw, int ldb,
    const float* __restrict__ bias,
    ushort* __restrict__ o_bf, int ld0,
    float* __restrict__ o_f32,
    int K, float scale)
{
    __shared__ __align__(1024) char smem[65536];  // A: 2x16K @0; B: 2x16K @32768
    const int t = threadIdx.x, w = t >> 6, l = t & 63, g = l >> 4, c = l & 15;
    const int wr = w >> 1, wc = w & 1;
    const long m0 = (long)blockIdx.y * 128, n0 = (long)blockIdx.x * 128;
    const size_t ldaB = (size_t)lda * 2, ldbB = (size_t)ldb * 2;
    const int swz = (c & 7) << 4;
    const int o0 = w * 1024 + l * 16;

    auto gsrc = [&](const char* base, size_t ldB, long r0, int o) {
        const int row = o >> 7, cb = o & 127;
        return base + (size_t)(r0 + row) * ldB + (cb ^ ((row & 7) << 4));
    };
    const char* aP0 = gsrc((const char*)A, ldaB, m0, o0);
    const char* aP1 = gsrc((const char*)A, ldaB, m0, o0 + 4096);
    const char* aP2 = gsrc((const char*)A, ldaB, m0, o0 + 8192);
    const char* aP3 = gsrc((const char*)A, ldaB, m0, o0 + 12288);
    const char* bP0 = gsrc((const char*)Bw, ldbB, n0, o0);
    const char* bP1 = gsrc((const char*)Bw, ldbB, n0, o0 + 4096);
    const char* bP2 = gsrc((const char*)Bw, ldbB, n0, o0 + 8192);
    const char* bP3 = gsrc((const char*)Bw, ldbB, n0, o0 + 12288);

    const int aRd0 = (wr * 64 + c) * 128 + ((g * 16) ^ swz);
    const int aRd1 = aRd0 ^ 64;
    const int bRd0 = 32768 + (wc * 64 + c) * 128 + ((g * 16) ^ swz);
    const int bRd1 = bRd0 ^ 64;

    f32x4 acc[4][4];
#pragma unroll
    for (int i = 0; i < 4; ++i)
#pragma unroll
        for (int j = 0; j < 4; ++j) acc[i][j] = (f32x4)0.0f;

    auto stage = [&](int slot) {
        char* Ab = smem + slot * 16384;
        char* Bb = smem + 32768 + slot * 16384;
        gload16(aP0, Ab + w * 1024);
        gload16(aP1, Ab + 4096 + w * 1024);
        gload16(aP2, Ab + 8192 + w * 1024);
        gload16(aP3, Ab + 12288 + w * 1024);
        gload16(bP0, Bb + w * 1024);
        gload16(bP1, Bb + 4096 + w * 1024);
        gload16(bP2, Bb + 8192 + w * 1024);
        gload16(bP3, Bb + 12288 + w * 1024);
        aP0 += 128; aP1 += 128; aP2 += 128; aP3 += 128;
        bP0 += 128; bP1 += 128; bP2 += 128; bP3 += 128;
    };

    const int nkt = K >> 6;
    stage(0);
    for (int kt = 0; kt < nkt; ++kt) {
        const bool pf = (kt + 1 < nkt);
        if (pf) {
            stage((kt + 1) & 1);
            asm volatile("s_waitcnt vmcnt(8)" ::: "memory");  // cur tile done, next in flight
        } else {
            asm volatile("s_waitcnt vmcnt(0)" ::: "memory");
        }
        __builtin_amdgcn_s_barrier();   // all waves' staging of cur visible
        const char* Ac = smem + (kt & 1) * 16384;
        const char* Bc = smem + (kt & 1) * 16384;   // + 32768 via bRd base
#pragma unroll
        for (int kf = 0; kf < 2; ++kf) {
            const int ar = kf ? aRd1 : aRd0, br = kf ? bRd1 : bRd0;
            bf16x8 af0 = *(const bf16x8*)(Ac + 0 + ar);
            bf16x8 af1 = *(const bf16x8*)(Ac + 2048 + ar);
            bf16x8 af2 = *(const bf16x8*)(Ac + 4096 + ar);
            bf16x8 af3 = *(const bf16x8*)(Ac + 6144 + ar);
            bf16x8 bf0 = *(const bf16x8*)(Bc + 0 + br);
            bf16x8 bf1 = *(const bf16x8*)(Bc + 2048 + br);
            bf16x8 bf2 = *(const bf16x8*)(Bc + 4096 + br);
            bf16x8 bf3 = *(const bf16x8*)(Bc + 6144 + br);
#pragma unroll
            for (int i = 0; i < 4; ++i) {
                const bf16x8 af = (i == 0) ? af0 : (i == 1) ? af1 : (i == 2) ? af2 : af3;
                acc[i][0] = MFMA16(af, bf0, acc[i][0]);
                acc[i][1] = MFMA16(af, bf1, acc[i][1]);
                acc[i][2] = MFMA16(af, bf2, acc[i][2]);
                acc[i][3] = MFMA16(af, bf3, acc[i][3]);
            }
        }
        if (pf) __builtin_amdgcn_s_barrier();   // seal reads before next stage overwrites
    }

    // epilogue: C/D layout col = l&15, row = (l>>4)*4 + jj
#pragma unroll
    for (int i = 0; i < 4; ++i)
#pragma unroll
        for (int j = 0; j < 4; ++j) {
            const long col = n0 + wc * 64 + j * 16 + c;
            const float bs = bias[col];
            const long rowb = m0 + wr * 64 + i * 16 + g * 4;
            if (EPI == 1) {
                ushort4 o;
                o.x = f2bf(acc[i][j][0] + bs);
                o.y = f2bf(acc[i][j][1] + bs);
                o.z = f2bf(acc[i][j][2] + bs);
                o.w = f2bf(acc[i][j][3] + bs);
                *(ushort4*)(o_bf + col * (long)ld0 + rowb) = o;
            } else {
#pragma unroll
                for (int jj = 0; jj < 4; ++jj) {
                    const long row = rowb + jj;
                    const float v = acc[i][j][jj] + bs;
                    if (EPI == 0) {
                        o_bf[row * (long)ld0 + col] = f2bf(v * scale);
                    } else if (EPI == 2) {
                        o_f32[row * (long)ld0 + col] = v;
                        o_bf[row * 2048 + col] = f2bf(v);
                    } else { // EPI == 3 : silu
                        const float sv = v / (1.0f + __expf(-v));
                        o_bf[row * (long)ld0 + col] = f2bf(sv);
                    }
                }
            }
        }
}

// ---------- flash attention: 32x32 MFMA, in-register P, no-max softmax ----------
// grid (S/128, H, B), 256 threads = 4 waves; wave owns 32 q-rows; KVBLK=64.
// qp PRE-SCALED by Dh^-0.5*log2(e); vT: 1024x(B*M) bf16 (transposed V).
// Swapped QK^T at 32x32: lane (c=l&31, hi=l>>5) owns S[q=c][m=crow(r,hi)],
// crow(r,hi)=(r&3)+8*(r>>2)+4*hi. No-max softmax: p=exp2(s) raw — a row-constant
// shift cancels in (Sum p*v)/(Sum p); |s|<=~10 so exp2 can't over/underflow.
// P goes to PV A-frags via cvt_pk + permlane32_swap (T12) — zero LDS for P.
// Denominator lacc via ones-MFMA (C cols identical -> lane-local per q-row).
__global__ __launch_bounds__(256, 2) void attn_fwd(
    const ushort* __restrict__ qp, const ushort* __restrict__ kp,
    const ushort* __restrict__ vT, ushort* __restrict__ out)
{
    __shared__ __align__(1024) char smem[49152];  // K: 3x8K @0; V: 3x8K @24576
    const int t = threadIdx.x, w = t >> 6, l = t & 63;
    const int c = l & 31, hi = l >> 5;
    const int b = blockIdx.z, h = blockIdx.y;
    const int s0w = blockIdx.x * 128 + w * 32;

    // Q B-frags: col=q=s0w+c, k = kc*16 + hi*8 + e
    const size_t qbase = ((size_t)b * 2048 + s0w + c) * 1024 + h * 64 + hi * 8;
    const bf16x8 qf0 = *(const bf16x8*)(qp + qbase);
    const bf16x8 qf1 = *(const bf16x8*)(qp + qbase + 16);
    const bf16x8 qf2 = *(const bf16x8*)(qp + qbase + 32);
    const bf16x8 qf3 = *(const bf16x8*)(qp + qbase + 48);

    const u16x8 ones_u = (u16x8)(ushort)0x3F80;   // bf16 1.0 x8
    const bf16x8 ones = __builtin_bit_cast(bf16x8, ones_u);

    f32x16 oacc0 = (f32x16)0.0f, oacc1 = (f32x16)0.0f, lacc = (f32x16)0.0f;

    // LDS read bases: row c (K: + st*4096 for k-rows 32..63; V: + dt*4096 for d 32..63)
    const int swz = (c & 7) << 4;
    const int rb = c * 128 + ((hi * 16) ^ swz);

    // staging (identical to R5): K tile [64 m][128B], V^T tile [64 d][128B]
    const char* kpB = (const char*)kp + (size_t)b * 4096 * 2048 + h * 128;
    const char* vTB = (const char*)vT + (size_t)h * 64 * 16384 + (size_t)b * 4096 * 2;
    const int o0 = w * 1024 + l * 16;
    auto mksrc = [&](const char* base, size_t ldB, int o) {
        const int row = o >> 7, cb = o & 127;
        return base + (size_t)row * ldB + (cb ^ ((row & 7) << 4));
    };
    const char* kg0 = mksrc(kpB, 2048, o0);
    const char* kg1 = mksrc(kpB, 2048, o0 + 4096);
    const char* vg0 = mksrc(vTB, 16384, o0);
    const char* vg1 = mksrc(vTB, 16384, o0 + 4096);

    auto stage = [&](int stK) {
        gload16(kg0, smem + stK + w * 1024);
        gload16(kg1, smem + stK + 4096 + w * 1024);
        gload16(vg0, smem + 24576 + stK + w * 1024);
        gload16(vg1, smem + 24576 + stK + 4096 + w * 1024);
        kg0 += 131072; kg1 += 131072; vg0 += 128; vg1 += 128;
    };

    stage(0);
    stage(8192);
    asm volatile("s_waitcnt vmcnt(4)" ::: "memory");
    __builtin_amdgcn_s_barrier();

    int rdK = 0, stK = 16384;
    for (int ti = 0; ti < 64; ++ti) {
        const bool pf = (ti < 62);
        if (pf) {
            stage(stK);
            stK = (stK == 16384) ? 0 : stK + 8192;
        }
        const char* Ksc = smem + rdK;
        const char* Vsc = smem + 24576 + rdK;

        // S^T = K Q^T, two 32x32 S-tiles (k-rows st*32..)
        f32x16 s0v = (f32x16)0.0f, s1v = (f32x16)0.0f;
        {
            bf16x8 k0;
            k0 = *(const bf16x8*)(Ksc + (rb ^ 0));         s0v = MFMA32(k0, qf0, s0v);
            k0 = *(const bf16x8*)(Ksc + (rb ^ 32));        s0v = MFMA32(k0, qf1, s0v);
            k0 = *(const bf16x8*)(Ksc + (rb ^ 64));        s0v = MFMA32(k0, qf2, s0v);
            k0 = *(const bf16x8*)(Ksc + (rb ^ 96));        s0v = MFMA32(k0, qf3, s0v);
            k0 = *(const bf16x8*)(Ksc + 4096 + (rb ^ 0));  s1v = MFMA32(k0, qf0, s1v);
            k0 = *(const bf16x8*)(Ksc + 4096 + (rb ^ 32)); s1v = MFMA32(k0, qf1, s1v);
            k0 = *(const bf16x8*)(Ksc + 4096 + (rb ^ 64)); s1v = MFMA32(k0, qf2, s1v);
            k0 = *(const bf16x8*)(Ksc + 4096 + (rb ^ 96)); s1v = MFMA32(k0, qf3, s1v);
        }

        // no-max softmax + T12 frag build + PV, per S-tile
#define PV_HALF(SV, MB0, MB1)                                                   \
        {                                                                       \
            const float p0 = exp2f(SV[0]),  p1 = exp2f(SV[1]);                  \
            const float p2 = exp2f(SV[2]),  p3 = exp2f(SV[3]);                  \
            const float p4 = exp2f(SV[4]),  p5 = exp2f(SV[5]);                  \
            const float p6 = exp2f(SV[6]),  p7 = exp2f(SV[7]);                  \
            const float p8 = exp2f(SV[8]),  p9 = exp2f(SV[9]);                  \
            const float pa_ = exp2f(SV[10]), pb_ = exp2f(SV[11]);               \
            const float pc_ = exp2f(SV[12]), pd_ = exp2f(SV[13]);               \
            const float pe_ = exp2f(SV[14]), pf_ = exp2f(SV[15]);               \
            const unsigned u0 = cvtpk(p0, p1), u1 = cvtpk(p2, p3);              \
            const unsigned u2 = cvtpk(p4, p5), u3 = cvtpk(p6, p7);              \
            const unsigned u4 = cvtpk(p8, p9), u5 = cvtpk(pa_, pb_);            \
            const unsigned u6 = cvtpk(pc_, pd_), u7 = cvtpk(pe_, pf_);          \
            const bf16x8 paA = pv_frag(u0, u1, u2, u3);   /* m-chunk MB0 */     \
            const bf16x8 paB = pv_frag(u4, u5, u6, u7);   /* m-chunk MB1 */     \
            bf16x8 vb;                                                          \
            lacc = MFMA32(paA, ones, lacc);                                     \
            vb = *(const bf16x8*)(Vsc + (rb ^ (MB0 * 32)));                     \
            oacc0 = MFMA32(paA, vb, oacc0);                                     \
            vb = *(const bf16x8*)(Vsc + 4096 + (rb ^ (MB0 * 32)));              \
            oacc1 = MFMA32(paA, vb, oacc1);                                     \
            lacc = MFMA32(paB, ones, lacc);                                     \
            vb = *(const bf16x8*)(Vsc + (rb ^ (MB1 * 32)));                     \
            oacc0 = MFMA32(paB, vb, oacc0);                                     \
            vb = *(const bf16x8*)(Vsc + 4096 + (rb ^ (MB1 * 32)));              \
            oacc1 = MFMA32(paB, vb, oacc1);                                     \
        }
        PV_HALF(s0v, 0, 1)
        PV_HALF(s1v, 2, 3)
#undef PV_HALF

        rdK = (rdK == 16384) ? 0 : rdK + 8192;
        if (pf) asm volatile("s_waitcnt vmcnt(4)" ::: "memory");
        else    asm volatile("s_waitcnt vmcnt(0)" ::: "memory");
        __builtin_amdgcn_s_barrier();
    }

    // epilogue: row q = crow(r,hi) = (r&3)+8*(r>>2)+4*hi; col d = c (+32)
    const size_t obase = ((size_t)b * 2048 + s0w) * 1024 + h * 64 + c;
#pragma unroll
    for (int r = 0; r < 16; ++r) {
        const int q = (r & 3) + 8 * (r >> 2) + 4 * hi;
        const float rinv = 1.0f / lacc[r];
        out[obase + (size_t)q * 1024]      = f2bf(oacc0[r] * rinv);
        out[obase + (size_t)q * 1024 + 32] = f2bf(oacc1[r] * rinv);
    }
}

// ---------- gate + residual ----------
__global__ __launch_bounds__(256) void gate_out_k(
    const ushort* __restrict__ gs, const float* __restrict__ Wg2,
    const float* __restrict__ bg2, const float* __restrict__ query,
    const float* __restrict__ retr, float* __restrict__ out)
{
    const int r = blockIdx.x, t = threadIdx.x, w = t >> 6, l = t & 63;
    ushort4 gv = ((const ushort4*)(gs + (size_t)r * 1024))[t];
    float4 wv = ((const float4*)Wg2)[t];
    float p = bf2f(gv.x) * wv.x + bf2f(gv.y) * wv.y + bf2f(gv.z) * wv.z + bf2f(gv.w) * wv.w;
    for (int m = 1; m < 64; m <<= 1) p += __shfl_xor(p, m);
    __shared__ float red[4];
    if (l == 0) red[w] = p;
    __syncthreads();
    const float dot = red[0] + red[1] + red[2] + red[3] + bg2[0];
    const float gate = 1.0f / (1.0f + __expf(-dot));
    float4 q = ((const float4*)(query + (size_t)r * 1024))[t];
    float4 rt = ((const float4*)(retr + (size_t)r * 1024))[t];
    float4 o;
    o.x = q.x + gate * rt.x; o.y = q.y + gate * rt.y;
    o.z = q.z + gate * rt.z; o.w = q.w + gate * rt.w;
    ((float4*)(out + (size_t)r * 1024))[t] = o;
}

// ---------- launcher ----------
extern "C" void kernel_launch(void* const* d_in, const int* in_sizes, int n_in,
                              void* d_out, int out_size, void* d_ws, size_t ws_size,
                              hipStream_t stream) {
    const float* query = (const float*)d_in[0];   // 2x2048x1024
    const float* mkeys = (const float*)d_in[1];   // 2x4096x768
    const float* mvals = (const float*)d_in[2];   // 2x4096x768
    const float* Wq  = (const float*)d_in[3];
    const float* bq  = (const float*)d_in[4];
    const float* Wk  = (const float*)d_in[5];
    const float* bk  = (const float*)d_in[6];
    const float* Wv  = (const float*)d_in[7];
    const float* bv  = (const float*)d_in[8];
    const float* Wo  = (const float*)d_in[9];
    const float* bo  = (const float*)d_in[10];
    const float* Wg1 = (const float*)d_in[11];
    const float* bg1 = (const float*)d_in[12];
    const float* Wg2 = (const float*)d_in[13];
    const float* bg2 = (const float*)d_in[14];
    float* outF = (float*)d_out;

    char* ws = (char*)d_ws;
    size_t off = 0;
    auto take = [&](size_t bytes) { char* p = ws + off; off += (bytes + 255) & ~(size_t)255; return p; };
    ushort* cat    = (ushort*)take((size_t)4096 * 2048 * 2); // [query_bf | retro_bf]
    ushort* mkbf   = (ushort*)take((size_t)8192 * 768 * 2);
    ushort* mvbf   = (ushort*)take((size_t)8192 * 768 * 2);
    ushort* wqbf   = (ushort*)take((size_t)1024 * 1024 * 2);
    ushort* wkbf   = (ushort*)take((size_t)1024 * 768 * 2);
    ushort* wvbf   = (ushort*)take((size_t)1024 * 768 * 2);
    ushort* wobf   = (ushort*)take((size_t)1024 * 1024 * 2);
    ushort* wg1bf  = (ushort*)take((size_t)1024 * 2048 * 2);
    ushort* qproj  = (ushort*)take((size_t)4096 * 1024 * 2);
    ushort* kproj  = (ushort*)take((size_t)8192 * 1024 * 2);
    ushort* vprojT = (ushort*)take((size_t)1024 * 8192 * 2);
    ushort* attno  = (ushort*)take((size_t)4096 * 1024 * 2);
    float*  retro  = (float*)take((size_t)4096 * 1024 * 4);
    ushort* gsilu  = (ushort*)take((size_t)4096 * 1024 * 2);

    // conversions (3 launches)
    cvt_query_cat<<<4096, 256, 0, stream>>>(query, cat);
    cvt_kv<<<2048, 256, 0, stream>>>(mkeys, mkbf, mvals, mvbf, 8192 * 768 / 4);
    cvt_weights<<<1024, 256, 0, stream>>>(Wq, wqbf, 1024 * 1024 / 4,
                                          Wk, wkbf, 1024 * 768 / 4,
                                          Wv, wvbf, 1024 * 768 / 4,
                                          Wo, wobf, 1024 * 1024 / 4,
                                          Wg1, wg1bf, 1024 * 2048 / 4);

    // Q = (query Wq^T + bq) * Dh^-0.5 * log2(e)   [base-2 softmax domain]
    const float qscale = 0.125f * 1.44269504088896340736f;
    gemm_bt<0><<<dim3(8, 32), 256, 0, stream>>>(cat, 2048, wqbf, 1024, bq, qproj, 1024, nullptr, 1024, qscale);
    // K = mk Wk^T + bk
    gemm_bt<0><<<dim3(8, 64), 256, 0, stream>>>(mkbf, 768, wkbf, 768, bk, kproj, 1024, nullptr, 768, 1.0f);
    // V^T = (mv Wv^T + bv)^T
    gemm_bt<1><<<dim3(8, 64), 256, 0, stream>>>(mvbf, 768, wvbf, 768, bv, vprojT, 8192, nullptr, 768, 1.0f);
    // attention
    attn_fwd<<<dim3(16, 16, 2), 256, 0, stream>>>(qproj, kproj, vprojT, attno);
    // retr_o = attn_out Wo^T + bo  -> f32 (residual) + bf16 into cat cols 1024..2047
    gemm_bt<2><<<dim3(8, 32), 256, 0, stream>>>(attno, 1024, wobf, 1024, bo, cat + 1024, 1024, retro, 1024, 1.0f);
    // g = silu([query; retr_o] Wg1^T + bg1)
    gemm_bt<3><<<dim3(8, 32), 256, 0, stream>>>(cat, 2048, wg1bf, 2048, bg1, gsilu, 1024, nullptr, 2048, 1.0f);
    // gate + residual
    gate_out_k<<<4096, 256, 0, stream>>>(gsilu, Wg2, bg2, query, retro, outF);
}

// Round 7
// 349.683 us; speedup vs baseline: 1.1602x; 1.0575x over previous
//
#include <hip/hip_runtime.h>

// ---------- types ----------
typedef __attribute__((ext_vector_type(8))) __bf16 bf16x8;    // MFMA A/B frag (4 VGPR)
typedef __attribute__((ext_vector_type(4))) float f32x4;      // 16x16 C/D frag
typedef __attribute__((ext_vector_type(16))) float f32x16;    // 32x32 C/D frag
typedef __attribute__((ext_vector_type(8))) unsigned short u16x8;
typedef __attribute__((ext_vector_type(4))) unsigned u32x4;

// fp32 -> bf16 (RNE)
__device__ __forceinline__ ushort f2bf(float x) {
    unsigned u = __builtin_bit_cast(unsigned, x);
    unsigned r = u + 0x7fffu + ((u >> 16) & 1u);
    return (ushort)(r >> 16);
}
__device__ __forceinline__ float bf2f(ushort u) {
    unsigned v = ((unsigned)u) << 16;
    return __builtin_bit_cast(float, v);
}

// packed f32x2 -> bf16x2 (T12)
__device__ __forceinline__ unsigned cvtpk(float lo, float hi) {
    unsigned r;
    asm("v_cvt_pk_bf16_f32 %0, %1, %2" : "=v"(r) : "v"(lo), "v"(hi));
    return r;
}

// bare v_exp_f32 (base-2): avoid OCML exp2f wrapper overhead
#define E2(x) __builtin_amdgcn_exp2f(x)

// async global->LDS, 16B/lane; LDS dest = wave-uniform base + lane*16
__device__ __forceinline__ void gload16(const void* g, void* l) {
    __builtin_amdgcn_global_load_lds(
        (const __attribute__((address_space(1))) void*)g,
        (__attribute__((address_space(3))) void*)l,
        16, 0, 0);
}

#define MFMA16(a, b, cIn) __builtin_amdgcn_mfma_f32_16x16x32_bf16((a), (b), (cIn), 0, 0, 0)
#define MFMA32(a, b, cIn) __builtin_amdgcn_mfma_f32_32x32x16_bf16((a), (b), (cIn), 0, 0, 0)

// T12 lane exchange: build PV A-frag from packed P words (no LDS bounce).
__device__ __forceinline__ bf16x8 pv_frag(unsigned ua, unsigned ub, unsigned uc, unsigned ud) {
    unsigned x1 = ua, y1 = uc, x2 = ub, y2 = ud;
    asm("v_permlane32_swap_b32 %0, %1" : "+v"(x1), "+v"(y1));
    asm("v_permlane32_swap_b32 %0, %1" : "+v"(x2), "+v"(y2));
    u32x4 wv; wv[0] = x1; wv[1] = x2; wv[2] = y1; wv[3] = y2;
    return __builtin_bit_cast(bf16x8, wv);
}

// ---------- conversion kernels ----------
__global__ __launch_bounds__(256) void cvt_kv(const float* __restrict__ a, ushort* __restrict__ ab,
                                              const float* __restrict__ bsrc, ushort* __restrict__ bb,
                                              int n4) {
    const int stride = gridDim.x * 256;
    for (int i = blockIdx.x * 256 + threadIdx.x; i < n4; i += stride) {
        float4 v = ((const float4*)a)[i];
        ushort4 o; o.x = f2bf(v.x); o.y = f2bf(v.y); o.z = f2bf(v.z); o.w = f2bf(v.w);
        ((ushort4*)ab)[i] = o;
    }
    for (int i = blockIdx.x * 256 + threadIdx.x; i < n4; i += stride) {
        float4 v = ((const float4*)bsrc)[i];
        ushort4 o; o.x = f2bf(v.x); o.y = f2bf(v.y); o.z = f2bf(v.z); o.w = f2bf(v.w);
        ((ushort4*)bb)[i] = o;
    }
}

__global__ __launch_bounds__(256) void cvt_weights(
    const float* __restrict__ s0, ushort* __restrict__ d0, int n0,
    const float* __restrict__ s1, ushort* __restrict__ d1, int n1,
    const float* __restrict__ s2, ushort* __restrict__ d2, int n2,
    const float* __restrict__ s3, ushort* __restrict__ d3, int n3,
    const float* __restrict__ s4, ushort* __restrict__ d4, int n4c) {
    const int stride = gridDim.x * 256;
    const int t0 = blockIdx.x * 256 + threadIdx.x;
#define CVT_SEG(S, D, N)                                                  \
    for (int i = t0; i < (N); i += stride) {                              \
        float4 v = ((const float4*)(S))[i];                               \
        ushort4 o; o.x = f2bf(v.x); o.y = f2bf(v.y);                      \
        o.z = f2bf(v.z); o.w = f2bf(v.w);                                 \
        ((ushort4*)(D))[i] = o;                                           \
    }
    CVT_SEG(s0, d0, n0) CVT_SEG(s1, d1, n1) CVT_SEG(s2, d2, n2)
    CVT_SEG(s3, d3, n3) CVT_SEG(s4, d4, n4c)
#undef CVT_SEG
}

__global__ __launch_bounds__(256) void cvt_query_cat(const float* __restrict__ in,
                                                     ushort* __restrict__ cat) {
    const int r = blockIdx.x, t = threadIdx.x;
    float4 v = ((const float4*)(in + (size_t)r * 1024))[t];
    ushort4 o;
    o.x = f2bf(v.x); o.y = f2bf(v.y); o.z = f2bf(v.z); o.w = f2bf(v.w);
    ((ushort4*)(cat + (size_t)r * 2048))[t] = o;
}

// ---------- fused multi-GEMM: C = A @ W^T (+bias), 4 sub-GEMMs in one launch ----------
// 128x128x64 tiles, 4 waves (2x2), acc 4x4, 2-slot dbuf, counted vmcnt(8).
// epi 0: bf16 (acc+bias)*scale; epi 1: bf16 transposed; epi 4: f32 acc only (no bias).
struct GemmDesc {
    const ushort* A; const ushort* Bw; const float* bias;
    ushort* obf; float* of32;
    int lda, ldb, ld0, nkt, epi, tiles_m, base;
    float scale;
};

__global__ __launch_bounds__(256, 2) void gemm_fused(GemmDesc d0, GemmDesc d1,
                                                     GemmDesc d2, GemmDesc d3) {
    __shared__ __align__(1024) char smem[65536];  // A: 2x16K @0; B: 2x16K @32768
    const int t = threadIdx.x, w = t >> 6, l = t & 63, g = l >> 4, c = l & 15;
    const int wr = w >> 1, wc = w & 1;
    const int bid0 = blockIdx.x;
    const int bid = (bid0 & 7) * 192 + (bid0 >> 3);   // XCD swizzle (1536 = 8*192)
    GemmDesc d = d3;
    if (bid < d1.base) d = d0;
    else if (bid < d2.base) d = d1;
    else if (bid < d3.base) d = d2;
    const int tix = bid - d.base;
    const int tm = tix % d.tiles_m, tn = tix / d.tiles_m;
    const long m0 = (long)tm * 128, n0 = (long)tn * 128;
    const size_t ldaB = (size_t)d.lda * 2, ldbB = (size_t)d.ldb * 2;
    const int swz = (c & 7) << 4;
    const int o0 = w * 1024 + l * 16;

    auto gsrc = [&](const char* base, size_t ldB, long r0, int o) {
        const int row = o >> 7, cb = o & 127;
        return base + (size_t)(r0 + row) * ldB + (cb ^ ((row & 7) << 4));
    };
    const char* aP0 = gsrc((const char*)d.A, ldaB, m0, o0);
    const char* aP1 = gsrc((const char*)d.A, ldaB, m0, o0 + 4096);
    const char* aP2 = gsrc((const char*)d.A, ldaB, m0, o0 + 8192);
    const char* aP3 = gsrc((const char*)d.A, ldaB, m0, o0 + 12288);
    const char* bP0 = gsrc((const char*)d.Bw, ldbB, n0, o0);
    const char* bP1 = gsrc((const char*)d.Bw, ldbB, n0, o0 + 4096);
    const char* bP2 = gsrc((const char*)d.Bw, ldbB, n0, o0 + 8192);
    const char* bP3 = gsrc((const char*)d.Bw, ldbB, n0, o0 + 12288);

    const int aRd0 = (wr * 64 + c) * 128 + ((g * 16) ^ swz);
    const int aRd1 = aRd0 ^ 64;
    const int bRd0 = 32768 + (wc * 64 + c) * 128 + ((g * 16) ^ swz);
    const int bRd1 = bRd0 ^ 64;

    f32x4 acc[4][4];
#pragma unroll
    for (int i = 0; i < 4; ++i)
#pragma unroll
        for (int j = 0; j < 4; ++j) acc[i][j] = (f32x4)0.0f;

    auto stage = [&](int slot) {
        char* Ab = smem + slot * 16384;
        char* Bb = smem + 32768 + slot * 16384;
        gload16(aP0, Ab + w * 1024);
        gload16(aP1, Ab + 4096 + w * 1024);
        gload16(aP2, Ab + 8192 + w * 1024);
        gload16(aP3, Ab + 12288 + w * 1024);
        gload16(bP0, Bb + w * 1024);
        gload16(bP1, Bb + 4096 + w * 1024);
        gload16(bP2, Bb + 8192 + w * 1024);
        gload16(bP3, Bb + 12288 + w * 1024);
        aP0 += 128; aP1 += 128; aP2 += 128; aP3 += 128;
        bP0 += 128; bP1 += 128; bP2 += 128; bP3 += 128;
    };

    const int nkt = d.nkt;
    stage(0);
    for (int kt = 0; kt < nkt; ++kt) {
        const bool pf = (kt + 1 < nkt);
        if (pf) {
            stage((kt + 1) & 1);
            asm volatile("s_waitcnt vmcnt(8)" ::: "memory");
        } else {
            asm volatile("s_waitcnt vmcnt(0)" ::: "memory");
        }
        __builtin_amdgcn_s_barrier();
        const char* Ac = smem + (kt & 1) * 16384;
        const char* Bc = smem + (kt & 1) * 16384;
#pragma unroll
        for (int kf = 0; kf < 2; ++kf) {
            const int ar = kf ? aRd1 : aRd0, br = kf ? bRd1 : bRd0;
            bf16x8 af0 = *(const bf16x8*)(Ac + 0 + ar);
            bf16x8 af1 = *(const bf16x8*)(Ac + 2048 + ar);
            bf16x8 af2 = *(const bf16x8*)(Ac + 4096 + ar);
            bf16x8 af3 = *(const bf16x8*)(Ac + 6144 + ar);
            bf16x8 bf0 = *(const bf16x8*)(Bc + 0 + br);
            bf16x8 bf1 = *(const bf16x8*)(Bc + 2048 + br);
            bf16x8 bf2 = *(const bf16x8*)(Bc + 4096 + br);
            bf16x8 bf3 = *(const bf16x8*)(Bc + 6144 + br);
#pragma unroll
            for (int i = 0; i < 4; ++i) {
                const bf16x8 af = (i == 0) ? af0 : (i == 1) ? af1 : (i == 2) ? af2 : af3;
                acc[i][0] = MFMA16(af, bf0, acc[i][0]);
                acc[i][1] = MFMA16(af, bf1, acc[i][1]);
                acc[i][2] = MFMA16(af, bf2, acc[i][2]);
                acc[i][3] = MFMA16(af, bf3, acc[i][3]);
            }
        }
        if (pf) __builtin_amdgcn_s_barrier();
    }

    // epilogue
#pragma unroll
    for (int i = 0; i < 4; ++i)
#pragma unroll
        for (int j = 0; j < 4; ++j) {
            const long col = n0 + wc * 64 + j * 16 + c;
            const long rowb = m0 + wr * 64 + i * 16 + g * 4;
            if (d.epi == 1) {
                const float bs = d.bias[col];
                ushort4 o;
                o.x = f2bf(acc[i][j][0] + bs);
                o.y = f2bf(acc[i][j][1] + bs);
                o.z = f2bf(acc[i][j][2] + bs);
                o.w = f2bf(acc[i][j][3] + bs);
                *(ushort4*)(d.obf + col * (long)d.ld0 + rowb) = o;
            } else if (d.epi == 4) {
#pragma unroll
                for (int jj = 0; jj < 4; ++jj)
                    d.of32[(rowb + jj) * (long)d.ld0 + col] = acc[i][j][jj];
            } else {  // epi 0
                const float bs = d.bias[col];
#pragma unroll
                for (int jj = 0; jj < 4; ++jj)
                    d.obf[(rowb + jj) * (long)d.ld0 + col] = f2bf((acc[i][j][jj] + bs) * d.scale);
            }
        }
}

// ---------- tail GEMM: 64M x 128N x 64K tiles (512 blocks -> 2-3/CU) ----------
// EPI 2: f32 out (retro) + bf16 into cat (row stride 2048)
// EPI 5: silu(acc + gpre + bias) -> bf16 (gpre read via o_f32)
template<int EPI>
__global__ __launch_bounds__(256, 2) void gemm_tail(
    const ushort* __restrict__ A, int lda,
    const ushort* __restrict__ Bw, int ldb,
    const float* __restrict__ bias,
    ushort* __restrict__ o_bf, int ld0,
    float* __restrict__ o_f32, int K) {
    __shared__ __align__(1024) char smem[49152];  // A: 2x8K @0; B: 2x16K @16384
    const int t = threadIdx.x, w = t >> 6, l = t & 63, g = l >> 4, c = l & 15;
    const int wr = w >> 1, wc = w & 1;
    const long m0 = (long)blockIdx.y * 64, n0 = (long)blockIdx.x * 128;
    const size_t ldaB = (size_t)lda * 2, ldbB = (size_t)ldb * 2;
    const int swz = (c & 7) << 4;
    const int o0 = w * 1024 + l * 16;

    auto gsrc = [&](const char* base, size_t ldB, long r0, int o) {
        const int row = o >> 7, cb = o & 127;
        return base + (size_t)(r0 + row) * ldB + (cb ^ ((row & 7) << 4));
    };
    const char* aP0 = gsrc((const char*)A, ldaB, m0, o0);
    const char* aP1 = gsrc((const char*)A, ldaB, m0, o0 + 4096);
    const char* bP0 = gsrc((const char*)Bw, ldbB, n0, o0);
    const char* bP1 = gsrc((const char*)Bw, ldbB, n0, o0 + 4096);
    const char* bP2 = gsrc((const char*)Bw, ldbB, n0, o0 + 8192);
    const char* bP3 = gsrc((const char*)Bw, ldbB, n0, o0 + 12288);

    const int aRd0 = (wr * 32 + c) * 128 + ((g * 16) ^ swz);
    const int aRd1 = aRd0 ^ 64;
    const int bRd0 = 16384 + (wc * 64 + c) * 128 + ((g * 16) ^ swz);
    const int bRd1 = bRd0 ^ 64;

    f32x4 acc[2][4];
#pragma unroll
    for (int i = 0; i < 2; ++i)
#pragma unroll
        for (int j = 0; j < 4; ++j) acc[i][j] = (f32x4)0.0f;

    auto stage = [&](int slot) {
        char* Ab = smem + slot * 8192;
        char* Bb = smem + 16384 + slot * 16384;
        gload16(aP0, Ab + w * 1024);
        gload16(aP1, Ab + 4096 + w * 1024);
        gload16(bP0, Bb + w * 1024);
        gload16(bP1, Bb + 4096 + w * 1024);
        gload16(bP2, Bb + 8192 + w * 1024);
        gload16(bP3, Bb + 12288 + w * 1024);
        aP0 += 128; aP1 += 128;
        bP0 += 128; bP1 += 128; bP2 += 128; bP3 += 128;
    };

    const int nkt = K >> 6;
    stage(0);
    for (int kt = 0; kt < nkt; ++kt) {
        const bool pf = (kt + 1 < nkt);
        if (pf) {
            stage((kt + 1) & 1);
            asm volatile("s_waitcnt vmcnt(6)" ::: "memory");
        } else {
            asm volatile("s_waitcnt vmcnt(0)" ::: "memory");
        }
        __builtin_amdgcn_s_barrier();
        const char* Ac = smem + (kt & 1) * 8192;
        const char* Bc = smem + (kt & 1) * 16384;
#pragma unroll
        for (int kf = 0; kf < 2; ++kf) {
            const int ar = kf ? aRd1 : aRd0, br = kf ? bRd1 : bRd0;
            bf16x8 af0 = *(const bf16x8*)(Ac + 0 + ar);
            bf16x8 af1 = *(const bf16x8*)(Ac + 2048 + ar);
            bf16x8 bf0 = *(const bf16x8*)(Bc + 0 + br);
            bf16x8 bf1 = *(const bf16x8*)(Bc + 2048 + br);
            bf16x8 bf2 = *(const bf16x8*)(Bc + 4096 + br);
            bf16x8 bf3 = *(const bf16x8*)(Bc + 6144 + br);
            acc[0][0] = MFMA16(af0, bf0, acc[0][0]);
            acc[0][1] = MFMA16(af0, bf1, acc[0][1]);
            acc[0][2] = MFMA16(af0, bf2, acc[0][2]);
            acc[0][3] = MFMA16(af0, bf3, acc[0][3]);
            acc[1][0] = MFMA16(af1, bf0, acc[1][0]);
            acc[1][1] = MFMA16(af1, bf1, acc[1][1]);
            acc[1][2] = MFMA16(af1, bf2, acc[1][2]);
            acc[1][3] = MFMA16(af1, bf3, acc[1][3]);
        }
        if (pf) __builtin_amdgcn_s_barrier();
    }

#pragma unroll
    for (int i = 0; i < 2; ++i)
#pragma unroll
        for (int j = 0; j < 4; ++j) {
            const long col = n0 + wc * 64 + j * 16 + c;
            const float bs = bias[col];
            const long rowb = m0 + wr * 32 + i * 16 + g * 4;
#pragma unroll
            for (int jj = 0; jj < 4; ++jj) {
                const long row = rowb + jj;
                if (EPI == 2) {
                    const float v = acc[i][j][jj] + bs;
                    o_f32[row * (long)ld0 + col] = v;
                    o_bf[row * 2048 + col] = f2bf(v);
                } else {  // EPI == 5 : silu(acc + gpre + bias)
                    const float v = acc[i][j][jj] + bs + o_f32[row * (long)ld0 + col];
                    const float sv = v / (1.0f + __expf(-v));
                    o_bf[row * (long)ld0 + col] = f2bf(sv);
                }
            }
        }
}

// ---------- flash attention: 32x32 MFMA, in-register P, no-max softmax ----------
// (structure identical to R6; exp2 via bare v_exp_f32; setprio around MFMA clusters)
__global__ __launch_bounds__(256, 2) void attn_fwd(
    const ushort* __restrict__ qp, const ushort* __restrict__ kp,
    const ushort* __restrict__ vT, ushort* __restrict__ out)
{
    __shared__ __align__(1024) char smem[49152];  // K: 3x8K @0; V: 3x8K @24576
    const int t = threadIdx.x, w = t >> 6, l = t & 63;
    const int c = l & 31, hi = l >> 5;
    const int b = blockIdx.z, h = blockIdx.y;
    const int s0w = blockIdx.x * 128 + w * 32;

    const size_t qbase = ((size_t)b * 2048 + s0w + c) * 1024 + h * 64 + hi * 8;
    const bf16x8 qf0 = *(const bf16x8*)(qp + qbase);
    const bf16x8 qf1 = *(const bf16x8*)(qp + qbase + 16);
    const bf16x8 qf2 = *(const bf16x8*)(qp + qbase + 32);
    const bf16x8 qf3 = *(const bf16x8*)(qp + qbase + 48);

    const u16x8 ones_u = (u16x8)(ushort)0x3F80;   // bf16 1.0 x8
    const bf16x8 ones = __builtin_bit_cast(bf16x8, ones_u);

    f32x16 oacc0 = (f32x16)0.0f, oacc1 = (f32x16)0.0f, lacc = (f32x16)0.0f;

    const int swz = (c & 7) << 4;
    const int rb = c * 128 + ((hi * 16) ^ swz);

    const char* kpB = (const char*)kp + (size_t)b * 4096 * 2048 + h * 128;
    const char* vTB = (const char*)vT + (size_t)h * 64 * 16384 + (size_t)b * 4096 * 2;
    const int o0 = w * 1024 + l * 16;
    auto mksrc = [&](const char* base, size_t ldB, int o) {
        const int row = o >> 7, cb = o & 127;
        return base + (size_t)row * ldB + (cb ^ ((row & 7) << 4));
    };
    const char* kg0 = mksrc(kpB, 2048, o0);
    const char* kg1 = mksrc(kpB, 2048, o0 + 4096);
    const char* vg0 = mksrc(vTB, 16384, o0);
    const char* vg1 = mksrc(vTB, 16384, o0 + 4096);

    auto stage = [&](int stK) {
        gload16(kg0, smem + stK + w * 1024);
        gload16(kg1, smem + stK + 4096 + w * 1024);
        gload16(vg0, smem + 24576 + stK + w * 1024);
        gload16(vg1, smem + 24576 + stK + 4096 + w * 1024);
        kg0 += 131072; kg1 += 131072; vg0 += 128; vg1 += 128;
    };

    stage(0);
    stage(8192);
    asm volatile("s_waitcnt vmcnt(4)" ::: "memory");
    __builtin_amdgcn_s_barrier();

    int rdK = 0, stK = 16384;
    for (int ti = 0; ti < 64; ++ti) {
        const bool pf = (ti < 62);
        if (pf) {
            stage(stK);
            stK = (stK == 16384) ? 0 : stK + 8192;
        }
        const char* Ksc = smem + rdK;
        const char* Vsc = smem + 24576 + rdK;

        // S^T = K Q^T, two 32x32 S-tiles
        f32x16 s0v = (f32x16)0.0f, s1v = (f32x16)0.0f;
        __builtin_amdgcn_s_setprio(1);
        {
            bf16x8 k0;
            k0 = *(const bf16x8*)(Ksc + (rb ^ 0));         s0v = MFMA32(k0, qf0, s0v);
            k0 = *(const bf16x8*)(Ksc + (rb ^ 32));        s0v = MFMA32(k0, qf1, s0v);
            k0 = *(const bf16x8*)(Ksc + (rb ^ 64));        s0v = MFMA32(k0, qf2, s0v);
            k0 = *(const bf16x8*)(Ksc + (rb ^ 96));        s0v = MFMA32(k0, qf3, s0v);
            k0 = *(const bf16x8*)(Ksc + 4096 + (rb ^ 0));  s1v = MFMA32(k0, qf0, s1v);
            k0 = *(const bf16x8*)(Ksc + 4096 + (rb ^ 32)); s1v = MFMA32(k0, qf1, s1v);
            k0 = *(const bf16x8*)(Ksc + 4096 + (rb ^ 64)); s1v = MFMA32(k0, qf2, s1v);
            k0 = *(const bf16x8*)(Ksc + 4096 + (rb ^ 96)); s1v = MFMA32(k0, qf3, s1v);
        }
        __builtin_amdgcn_s_setprio(0);

        // no-max softmax (p = exp2 raw, shift cancels in the ratio) + T12 + PV
#define PV_HALF(SV, MB0, MB1)                                                   \
        {                                                                       \
            const float p0 = E2(SV[0]),  p1 = E2(SV[1]);                        \
            const float p2 = E2(SV[2]),  p3 = E2(SV[3]);                        \
            const float p4 = E2(SV[4]),  p5 = E2(SV[5]);                        \
            const float p6 = E2(SV[6]),  p7 = E2(SV[7]);                        \
            const float p8 = E2(SV[8]),  p9 = E2(SV[9]);                        \
            const float pa_ = E2(SV[10]), pb_ = E2(SV[11]);                     \
            const float pc_ = E2(SV[12]), pd_ = E2(SV[13]);                     \
            const float pe_ = E2(SV[14]), pf_ = E2(SV[15]);                     \
            const unsigned u0 = cvtpk(p0, p1), u1 = cvtpk(p2, p3);              \
            const unsigned u2 = cvtpk(p4, p5), u3 = cvtpk(p6, p7);              \
            const unsigned u4 = cvtpk(p8, p9), u5 = cvtpk(pa_, pb_);            \
            const unsigned u6 = cvtpk(pc_, pd_), u7 = cvtpk(pe_, pf_);          \
            const bf16x8 paA = pv_frag(u0, u1, u2, u3);                         \
            const bf16x8 paB = pv_frag(u4, u5, u6, u7);                         \
            bf16x8 vb;                                                          \
            __builtin_amdgcn_s_setprio(1);                                      \
            lacc = MFMA32(paA, ones, lacc);                                     \
            vb = *(const bf16x8*)(Vsc + (rb ^ (MB0 * 32)));                     \
            oacc0 = MFMA32(paA, vb, oacc0);                                     \
            vb = *(const bf16x8*)(Vsc + 4096 + (rb ^ (MB0 * 32)));              \
            oacc1 = MFMA32(paA, vb, oacc1);                                     \
            lacc = MFMA32(paB, ones, lacc);                                     \
            vb = *(const bf16x8*)(Vsc + (rb ^ (MB1 * 32)));                     \
            oacc0 = MFMA32(paB, vb, oacc0);                                     \
            vb = *(const bf16x8*)(Vsc + 4096 + (rb ^ (MB1 * 32)));              \
            oacc1 = MFMA32(paB, vb, oacc1);                                     \
            __builtin_amdgcn_s_setprio(0);                                      \
        }
        PV_HALF(s0v, 0, 1)
        PV_HALF(s1v, 2, 3)
#undef PV_HALF

        rdK = (rdK == 16384) ? 0 : rdK + 8192;
        if (pf) asm volatile("s_waitcnt vmcnt(4)" ::: "memory");
        else    asm volatile("s_waitcnt vmcnt(0)" ::: "memory");
        __builtin_amdgcn_s_barrier();
    }

    // epilogue: row q = (r&3)+8*(r>>2)+4*hi; col d = c (+32)
    const size_t obase = ((size_t)b * 2048 + s0w) * 1024 + h * 64 + c;
#pragma unroll
    for (int r = 0; r < 16; ++r) {
        const int q = (r & 3) + 8 * (r >> 2) + 4 * hi;
        const float rinv = 1.0f / lacc[r];
        out[obase + (size_t)q * 1024]      = f2bf(oacc0[r] * rinv);
        out[obase + (size_t)q * 1024 + 32] = f2bf(oacc1[r] * rinv);
    }
}

// ---------- gate + residual ----------
__global__ __launch_bounds__(256) void gate_out_k(
    const ushort* __restrict__ gs, const float* __restrict__ Wg2,
    const float* __restrict__ bg2, const float* __restrict__ query,
    const float* __restrict__ retr, float* __restrict__ out)
{
    const int r = blockIdx.x, t = threadIdx.x, w = t >> 6, l = t & 63;
    ushort4 gv = ((const ushort4*)(gs + (size_t)r * 1024))[t];
    float4 wv = ((const float4*)Wg2)[t];
    float p = bf2f(gv.x) * wv.x + bf2f(gv.y) * wv.y + bf2f(gv.z) * wv.z + bf2f(gv.w) * wv.w;
    for (int m = 1; m < 64; m <<= 1) p += __shfl_xor(p, m);
    __shared__ float red[4];
    if (l == 0) red[w] = p;
    __syncthreads();
    const float dot = red[0] + red[1] + red[2] + red[3] + bg2[0];
    const float gate = 1.0f / (1.0f + __expf(-dot));
    float4 q = ((const float4*)(query + (size_t)r * 1024))[t];
    float4 rt = ((const float4*)(retr + (size_t)r * 1024))[t];
    float4 o;
    o.x = q.x + gate * rt.x; o.y = q.y + gate * rt.y;
    o.z = q.z + gate * rt.z; o.w = q.w + gate * rt.w;
    ((float4*)(out + (size_t)r * 1024))[t] = o;
}

// ---------- launcher ----------
extern "C" void kernel_launch(void* const* d_in, const int* in_sizes, int n_in,
                              void* d_out, int out_size, void* d_ws, size_t ws_size,
                              hipStream_t stream) {
    const float* query = (const float*)d_in[0];   // 2x2048x1024
    const float* mkeys = (const float*)d_in[1];   // 2x4096x768
    const float* mvals = (const float*)d_in[2];   // 2x4096x768
    const float* Wq  = (const float*)d_in[3];
    const float* bq  = (const float*)d_in[4];
    const float* Wk  = (const float*)d_in[5];
    const float* bk  = (const float*)d_in[6];
    const float* Wv  = (const float*)d_in[7];
    const float* bv  = (const float*)d_in[8];
    const float* Wo  = (const float*)d_in[9];
    const float* bo  = (const float*)d_in[10];
    const float* Wg1 = (const float*)d_in[11];
    const float* bg1 = (const float*)d_in[12];
    const float* Wg2 = (const float*)d_in[13];
    const float* bg2 = (const float*)d_in[14];
    float* outF = (float*)d_out;

    char* ws = (char*)d_ws;
    size_t off = 0;
    auto take = [&](size_t bytes) { char* p = ws + off; off += (bytes + 255) & ~(size_t)255; return p; };
    ushort* cat    = (ushort*)take((size_t)4096 * 2048 * 2); // [query_bf | retro_bf]
    ushort* mkbf   = (ushort*)take((size_t)8192 * 768 * 2);
    ushort* mvbf   = (ushort*)take((size_t)8192 * 768 * 2);
    ushort* wqbf   = (ushort*)take((size_t)1024 * 1024 * 2);
    ushort* wkbf   = (ushort*)take((size_t)1024 * 768 * 2);
    ushort* wvbf   = (ushort*)take((size_t)1024 * 768 * 2);
    ushort* wobf   = (ushort*)take((size_t)1024 * 1024 * 2);
    ushort* wg1bf  = (ushort*)take((size_t)1024 * 2048 * 2);
    ushort* qproj  = (ushort*)take((size_t)4096 * 1024 * 2);
    ushort* kproj  = (ushort*)take((size_t)8192 * 1024 * 2);
    ushort* vprojT = (ushort*)take((size_t)1024 * 8192 * 2);
    ushort* attno  = (ushort*)take((size_t)4096 * 1024 * 2);
    float*  retro  = (float*)take((size_t)4096 * 1024 * 4);
    ushort* gsilu  = (ushort*)take((size_t)4096 * 1024 * 2);
    float*  gpre   = (float*)take((size_t)4096 * 1024 * 4);

    // conversions
    cvt_query_cat<<<4096, 256, 0, stream>>>(query, cat);
    cvt_kv<<<2048, 256, 0, stream>>>(mkeys, mkbf, mvals, mvbf, 8192 * 768 / 4);
    cvt_weights<<<1024, 256, 0, stream>>>(Wq, wqbf, 1024 * 1024 / 4,
                                          Wk, wkbf, 1024 * 768 / 4,
                                          Wv, wvbf, 1024 * 768 / 4,
                                          Wo, wobf, 1024 * 1024 / 4,
                                          Wg1, wg1bf, 1024 * 2048 / 4);

    // fused projections: Qproj (scaled), Kproj, VprojT, Wg1a (query half -> gpre f32)
    const float qscale = 0.125f * 1.44269504088896340736f;  // Dh^-0.5 * log2(e)
    GemmDesc dQ { cat,   wqbf,          bq,  qproj,  nullptr, 2048, 1024, 1024, 16, 0, 32,    0, qscale };
    GemmDesc dK { mkbf,  wkbf,          bk,  kproj,  nullptr,  768,  768, 1024, 12, 0, 64,  256, 1.0f };
    GemmDesc dV { mvbf,  wvbf,          bv,  vprojT, nullptr,  768,  768, 8192, 12, 1, 64,  768, 1.0f };
    GemmDesc dG { cat,   wg1bf,         bg1, nullptr, gpre,   2048, 2048, 1024, 16, 4, 32, 1280, 1.0f };
    gemm_fused<<<1536, 256, 0, stream>>>(dQ, dK, dV, dG);

    // attention
    attn_fwd<<<dim3(16, 16, 2), 256, 0, stream>>>(qproj, kproj, vprojT, attno);

    // retr_o = attn_out Wo^T + bo -> f32 retro + bf16 into cat cols 1024..2047
    gemm_tail<2><<<dim3(8, 64), 256, 0, stream>>>(attno, 1024, wobf, 1024, bo,
                                                  cat + 1024, 1024, retro, 1024);
    // g = silu(gpre + retro_bf @ Wg1[:,1024:]^T + bg1)
    gemm_tail<5><<<dim3(8, 64), 256, 0, stream>>>(cat + 1024, 2048, wg1bf + 1024, 2048, bg1,
                                                  gsilu, 1024, gpre, 1024);
    // gate + residual
    gate_out_k<<<4096, 256, 0, stream>>>(gsilu, Wg2, bg2, query, retro, outF);
}